// Round 1
// baseline (2189.999 us; speedup 1.0000x reference)
//
#include <hip/hip_runtime.h>
#include <cstdint>
#include <cmath>

// Problem constants (fixed by reference setup_inputs)
constexpr int Bn = 4, Cn = 19, Hn = 512, Wn = 1024;
constexpr int HW  = Hn * Wn;            // 524288 = 2^19
constexpr int Nn  = Bn * HW;            // 2097152 = 2^21
constexpr int N4  = Nn / 4;
constexpr int NB  = 15;                 // NBINS
constexpr int NQ  = 30;                 // rank queries per class
constexpr int REP = 8;                  // histogram replicas (atomic contention)

// ---------------------------------------------------------------------------
// Pass 1: softmax (all classes) + write conf for group classes + hi-16 hist
// ---------------------------------------------------------------------------
__global__ __launch_bounds__(256) void k_softmax(
    const float* __restrict__ lg, float* __restrict__ conf,
    unsigned* __restrict__ hist, int c0, int gc)
{
    int t = blockIdx.x * 256 + threadIdx.x;
    if (t >= N4) return;
    int n  = t * 4;
    int b  = n >> 19;
    int hw = n & (HW - 1);
    const float* base = lg + ((size_t)(b * Cn) << 19) + hw;

    float4 x[Cn];
#pragma unroll
    for (int c = 0; c < Cn; c++)
        x[c] = *reinterpret_cast<const float4*>(base + ((size_t)c << 19));

    float4 m = x[0];
#pragma unroll
    for (int c = 1; c < Cn; c++) {
        m.x = fmaxf(m.x, x[c].x); m.y = fmaxf(m.y, x[c].y);
        m.z = fmaxf(m.z, x[c].z); m.w = fmaxf(m.w, x[c].w);
    }
    float4 s = make_float4(0.f, 0.f, 0.f, 0.f);
#pragma unroll
    for (int c = 0; c < Cn; c++) {
        x[c].x = __expf(x[c].x - m.x); s.x += x[c].x;
        x[c].y = __expf(x[c].y - m.y); s.y += x[c].y;
        x[c].z = __expf(x[c].z - m.z); s.z += x[c].z;
        x[c].w = __expf(x[c].w - m.w); s.w += x[c].w;
    }
    float4 inv = make_float4(1.f / s.x, 1.f / s.y, 1.f / s.z, 1.f / s.w);

    int rep = blockIdx.x & (REP - 1);
#pragma unroll
    for (int c = 0; c < Cn; c++) {
        if (c < c0 || c >= c0 + gc) continue;       // uniform predicate, keeps x[] static-indexed
        float4 v;
        v.x = x[c].x * inv.x; v.y = x[c].y * inv.y;
        v.z = x[c].z * inv.z; v.w = x[c].w * inv.w;
        *reinterpret_cast<float4*>(conf + (size_t)(c - c0) * Nn + n) = v;
        unsigned hb = ((unsigned)(rep * gc + (c - c0))) << 16;
        atomicAdd(&hist[hb + (__float_as_uint(v.x) >> 16)], 1u);
        atomicAdd(&hist[hb + (__float_as_uint(v.y) >> 16)], 1u);
        atomicAdd(&hist[hb + (__float_as_uint(v.z) >> 16)], 1u);
        atomicAdd(&hist[hb + (__float_as_uint(v.w) >> 16)], 1u);
    }
}

// ---------------------------------------------------------------------------
// Sum the REP histogram replicas into cum16 (pre-scan)
// ---------------------------------------------------------------------------
__global__ void k_redsum(const unsigned* __restrict__ hist,
                         unsigned* __restrict__ cum, int gc)
{
    int i = blockIdx.x * 256 + threadIdx.x;
    if (i >= gc * 65536) return;
    int cg = i >> 16, bin = i & 65535;
    unsigned s = 0;
#pragma unroll
    for (int r = 0; r < REP; r++)
        s += hist[(((size_t)(r * gc + cg)) << 16) + bin];
    cum[i] = s;
}

// ---------------------------------------------------------------------------
// In-place inclusive scan of each class's 65536-bin histogram
// ---------------------------------------------------------------------------
__global__ __launch_bounds__(1024) void k_scan16(unsigned* __restrict__ cum)
{
    int cg = blockIdx.x, t = threadIdx.x;
    unsigned* c = cum + ((size_t)cg << 16);
    int base = t * 64;
    unsigned s = 0;
    for (int k = 0; k < 64; k++) s += c[base + k];
    __shared__ unsigned ls[1024];
    ls[t] = s; __syncthreads();
    for (int off = 1; off < 1024; off <<= 1) {
        unsigned v = (t >= off) ? ls[t - off] : 0u;
        __syncthreads();
        ls[t] += v;
        __syncthreads();
    }
    unsigned run = ls[t] - s;
    for (int k = 0; k < 64; k++) { run += c[base + k]; c[base + k] = run; }
}

// rank of query slot s: 0 -> 0; 29 -> N-1; 2k-1 -> floor(k*N/15); 2k -> +1
__device__ __forceinline__ long long rank_of_slot(int s)
{
    if (s == 0)  return 0;
    if (s == 29) return (long long)Nn - 1;
    int k = (s & 1) ? ((s + 1) >> 1) : (s >> 1);
    double pos = (double)k * (double)Nn / 15.0;
    long long ik = (long long)floor(pos);
    return (s & 1) ? ik : ik + 1;
}

// ---------------------------------------------------------------------------
// Locate each rank's hi-16 bucket + residual rank; build sorted prefix list
// ---------------------------------------------------------------------------
__global__ void k_find16(const unsigned* __restrict__ cum,
                         unsigned* __restrict__ qprefix, unsigned* __restrict__ qresid,
                         unsigned* __restrict__ ulist, unsigned* __restrict__ uslot, int gc)
{
    int t = threadIdx.x, cg = t >> 5, q = t & 31;
    __shared__ unsigned sp[19 * 32];
    unsigned p = 0xFFFFFFFFu, resid = 0;
    bool active = (q < NQ);
    if (active) {
        long long r = rank_of_slot(q);
        const unsigned* c = cum + ((size_t)cg << 16);
        unsigned pos = 0;
#pragma unroll
        for (int st = 32768; st >= 1; st >>= 1) {
            unsigned np = pos + st;
            if (c[np - 1] <= (unsigned)r) pos = np;
        }
        unsigned prev = pos ? c[pos - 1] : 0u;
        p = pos; resid = (unsigned)r - prev;
    }
    sp[t] = p;
    __syncthreads();
    if (active) {
        const unsigned* row = sp + cg * 32;
        int rfull = 0, less = 0;
        for (int j = 0; j < NQ; j++) {
            unsigned pj = row[j];
            less  += (pj < p);
            rfull += (pj < p) || (pj == p && j < q);
        }
        qprefix[t] = p; qresid[t] = resid; uslot[t] = (unsigned)less;
        ulist[cg * 32 + rfull] = p;
    } else {
        ulist[cg * 32 + q] = 0xFFFFFFFFu;  // pad slots 30,31
    }
}

// ---------------------------------------------------------------------------
// Refinement: histogram next byte for elements matching a target prefix.
// L=0: match hi16, hist bits[15:8].  L=1: match hi24, hist bits[7:0].
// ---------------------------------------------------------------------------
template <int L>
__global__ __launch_bounds__(256) void k_refine(
    const float* __restrict__ conf, const unsigned* __restrict__ ulist,
    unsigned* __restrict__ qhist, int gc)
{
    int cg = blockIdx.x >> 5, chunk = blockIdx.x & 31;
    int tid = threadIdx.x;
    __shared__ unsigned ul[32];
    __shared__ unsigned h[8192];
    for (int i = tid; i < 8192; i += 256) h[i] = 0;
    if (tid < 32) ul[tid] = ulist[cg * 32 + tid];
    __syncthreads();

    const float4* p = reinterpret_cast<const float4*>(
        conf + (size_t)cg * Nn + (size_t)chunk * 65536);
    for (int it = 0; it < 64; it++) {
        float4 v = p[it * 256 + tid];
        unsigned bb[4] = { __float_as_uint(v.x), __float_as_uint(v.y),
                           __float_as_uint(v.z), __float_as_uint(v.w) };
#pragma unroll
        for (int j = 0; j < 4; j++) {
            unsigned bits = bb[j];
            unsigned key  = (L == 0) ? (bits >> 16) : (bits >> 8);
            unsigned byte = (L == 0) ? ((bits >> 8) & 255u) : (bits & 255u);
            unsigned pos = (ul[15] < key) ? 16u : 0u;     // branchless lower_bound(32)
            pos += (ul[pos + 7] < key) ? 8u : 0u;
            pos += (ul[pos + 3] < key) ? 4u : 0u;
            pos += (ul[pos + 1] < key) ? 2u : 0u;
            pos += (ul[pos]     < key) ? 1u : 0u;
            if (pos < 32u && ul[pos] == key)
                atomicAdd(&h[(pos << 8) + byte], 1u);
        }
    }
    __syncthreads();
    for (int i = tid; i < 8192; i += 256) {
        unsigned v = h[i];
        if (v) atomicAdd(&qhist[((size_t)cg << 13) + i], v);
    }
}

// ---------------------------------------------------------------------------
// Scan 256-bin query histograms; level 0 -> extend prefix, rebuild sorted
// list; level 1 -> final 32-bit value + edges.
// ---------------------------------------------------------------------------
__global__ void k_scan256(const unsigned* __restrict__ qhist,
                          unsigned* __restrict__ qprefix, unsigned* __restrict__ qresid,
                          unsigned* __restrict__ uslot, unsigned* __restrict__ ulist_next,
                          float* __restrict__ edges, int gc, int c0, int level)
{
    int t = threadIdx.x, cg = t >> 5, q = t & 31;
    bool active = (q < NQ);
    unsigned np = 0xFFFFFFFFu;
    if (active) {
        unsigned slot = uslot[t];
        unsigned r = qresid[t];
        const unsigned* hb = qhist + ((size_t)cg << 13) + (slot << 8);
        unsigned cum = 0, byte = 255, nr = r;
        int found = 0;
        for (int b2 = 0; b2 < 256; b2++) {
            unsigned cb = hb[b2];
            if (!found && r < cum + cb) { byte = (unsigned)b2; nr = r - cum; found = 1; }
            cum += cb;
        }
        np = (qprefix[t] << 8) | byte;
        qresid[t] = nr;
        qprefix[t] = np;
    }
    if (level == 0) {
        __shared__ unsigned sp[19 * 32];
        sp[t] = active ? np : 0xFFFFFFFFu;
        __syncthreads();
        if (active) {
            const unsigned* row = sp + cg * 32;
            int rfull = 0, less = 0;
            for (int j = 0; j < NQ; j++) {
                unsigned pj = row[j];
                less  += (pj < np);
                rfull += (pj < np) || (pj == np && j < q);
            }
            uslot[t] = (unsigned)less;
            ulist_next[cg * 32 + rfull] = np;
        } else {
            ulist_next[cg * 32 + q] = 0xFFFFFFFFu;
        }
    } else {
        __shared__ float sv[19 * 32];
        sv[t] = active ? __uint_as_float(np) : 0.f;
        __syncthreads();
        if (q < 16) {
            const float* vals = sv + cg * 32;
            float e;
            if (q == 0)       e = vals[0];
            else if (q == 15) e = vals[29];
            else {
                double pos = (double)q * (double)Nn / 15.0;
                double fr  = pos - floor(pos);
                float v0 = vals[2 * q - 1], v1 = vals[2 * q];
                e = v0 + (float)fr * (v1 - v0);
            }
            edges[(size_t)(c0 + cg) * 16 + q] = e;
        }
    }
}

// ---------------------------------------------------------------------------
// Binning + accumulation (count, sum_conf, sum_correct per class/bin)
// ---------------------------------------------------------------------------
__global__ __launch_bounds__(256) void k_bin(
    const float* __restrict__ conf, const int* __restrict__ labels,
    const float* __restrict__ edges, float* __restrict__ accum, int c0, int gc)
{
    __shared__ float eL[19 * 16];
    __shared__ float acc[19 * 45];
    int tid = threadIdx.x;
    for (int i = tid; i < gc * 45; i += 256) acc[i] = 0.f;
    for (int i = tid; i < gc * 16; i += 256) eL[i] = edges[(size_t)c0 * 16 + i];
    __syncthreads();

    int t = blockIdx.x * 256 + tid;
    if (t < N4) {
        int n = t * 4;
        int4 lab = *reinterpret_cast<const int4*>(labels + n);
        int lb[4] = { lab.x, lab.y, lab.z, lab.w };
        for (int cg = 0; cg < gc; cg++) {
            float4 v = *reinterpret_cast<const float4*>(conf + (size_t)cg * Nn + n);
            int c = c0 + cg;
            const float* e = eL + cg * 16;
            float vv[4] = { v.x, v.y, v.z, v.w };
#pragma unroll
            for (int j = 0; j < 4; j++) {
                int cnt = 0;
#pragma unroll
                for (int i = 0; i < 16; i++) cnt += (e[i] < vv[j]) ? 1 : 0;
                int idx = cnt - 1;                    // searchsorted(left) - 1
                if (idx >= 0 && idx < NB) {
                    float* a = acc + (cg * NB + idx) * 3;
                    atomicAdd(a, 1.f);
                    atomicAdd(a + 1, vv[j]);
                    if (lb[j] == c) atomicAdd(a + 2, 1.f);
                }
            }
        }
    }
    __syncthreads();
    for (int i = tid; i < gc * 45; i += 256) {
        float v = acc[i];
        if (v != 0.f) atomicAdd(&accum[(size_t)c0 * 45 + i], v);
    }
}

// ---------------------------------------------------------------------------
// Finalize: per-class aece + mean
// ---------------------------------------------------------------------------
__global__ void k_final(const float* __restrict__ accum, float* __restrict__ out)
{
    int c = threadIdx.x;
    __shared__ float pcs[Cn];
    if (c < Cn) {
        float pc = 0.f;
        for (int j = 0; j < NB; j++) {
            float cnt = accum[(c * NB + j) * 3];
            if (cnt > 0.f) {
                float sc  = accum[(c * NB + j) * 3 + 1];
                float scr = accum[(c * NB + j) * 3 + 2];
                float a   = scr / cnt;
                float avg = sc / cnt;
                float prop = cnt / (float)Nn;
                pc += fabsf(avg - a) * prop;
            }
        }
        pcs[c] = pc;
        out[1 + c] = pc;
    }
    __syncthreads();
    if (c == 0) {
        float s = 0.f;
        for (int j = 0; j < Cn; j++) s += pcs[j];
        out[0] = s / (float)Cn;
    }
}

// ---------------------------------------------------------------------------
extern "C" void kernel_launch(void* const* d_in, const int* in_sizes, int n_in,
                              void* d_out, int out_size, void* d_ws, size_t ws_size,
                              hipStream_t stream)
{
    const float* logits = (const float*)d_in[0];
    const int*   labels = (const int*)d_in[1];
    float* out = (float*)d_out;
    char*  ws  = (char*)d_ws;

    // Class-group sizing from available workspace
    size_t per_class = (size_t)Nn * 4            // conf row
                     + (size_t)REP * 65536 * 4   // hist replicas
                     + (size_t)65536 * 4         // cum
                     + 2ull * 32 * 256 * 4;      // qhistA+B share
    size_t fixed = 65536;
    int gc = (ws_size > fixed) ? (int)((ws_size - fixed) / per_class) : 1;
    if (gc > Cn) gc = Cn;
    if (gc < 1)  gc = 1;
    int ng = (Cn + gc - 1) / gc;

    size_t off = 0;
    auto alloc = [&](size_t bytes) { size_t o = off; off += (bytes + 255) & ~(size_t)255; return o; };
    float*    conf    = (float*)(ws + alloc((size_t)gc * Nn * 4));
    unsigned* hist16  = (unsigned*)(ws + alloc((size_t)REP * gc * 65536 * 4));
    unsigned* qhistA  = (unsigned*)(ws + alloc((size_t)gc * 32 * 256 * 4));
    unsigned* qhistB  = (unsigned*)(ws + alloc((size_t)gc * 32 * 256 * 4));
    unsigned* cum16   = (unsigned*)(ws + alloc((size_t)gc * 65536 * 4));
    unsigned* qprefix = (unsigned*)(ws + alloc(19 * 32 * 4));
    unsigned* qresid  = (unsigned*)(ws + alloc(19 * 32 * 4));
    unsigned* uslot   = (unsigned*)(ws + alloc(19 * 32 * 4));
    unsigned* ulist16 = (unsigned*)(ws + alloc(19 * 32 * 4));
    unsigned* ulist24 = (unsigned*)(ws + alloc(19 * 32 * 4));
    float*    edges   = (float*)(ws + alloc(19 * 16 * 4));
    float*    accum   = (float*)(ws + alloc(19 * 45 * 4));

    hipMemsetAsync(accum, 0, 19 * 45 * 4, stream);
    for (int g = 0; g < ng; g++) {
        int c0 = g * gc;
        int gcc = (Cn - c0 < gc) ? (Cn - c0) : gc;
        hipMemsetAsync(hist16, 0, (size_t)REP * gcc * 65536 * 4, stream);
        hipMemsetAsync(qhistA, 0, (size_t)gcc * 32 * 256 * 4, stream);
        hipMemsetAsync(qhistB, 0, (size_t)gcc * 32 * 256 * 4, stream);

        k_softmax<<<N4 / 256, 256, 0, stream>>>(logits, conf, hist16, c0, gcc);
        k_redsum<<<(gcc * 65536 + 255) / 256, 256, 0, stream>>>(hist16, cum16, gcc);
        k_scan16<<<gcc, 1024, 0, stream>>>(cum16);
        k_find16<<<1, gcc * 32, 0, stream>>>(cum16, qprefix, qresid, ulist16, uslot, gcc);
        k_refine<0><<<gcc * 32, 256, 0, stream>>>(conf, ulist16, qhistA, gcc);
        k_scan256<<<1, gcc * 32, 0, stream>>>(qhistA, qprefix, qresid, uslot, ulist24,
                                              edges, gcc, c0, 0);
        k_refine<1><<<gcc * 32, 256, 0, stream>>>(conf, ulist24, qhistB, gcc);
        k_scan256<<<1, gcc * 32, 0, stream>>>(qhistB, qprefix, qresid, uslot, ulist24,
                                              edges, gcc, c0, 1);
        k_bin<<<N4 / 256, 256, 0, stream>>>(conf, labels, edges, accum, c0, gcc);
    }
    k_final<<<1, 64, 0, stream>>>(accum, out);
}

// Round 3
// 1138.235 us; speedup vs baseline: 1.9240x; 1.9240x over previous
//
#include <hip/hip_runtime.h>
#include <cstdint>
#include <cmath>

// Problem constants (fixed by reference setup_inputs)
constexpr int Bn = 4, Cn = 19, Hn = 512, Wn = 1024;
constexpr int HW  = Hn * Wn;            // 524288 = 2^19
constexpr int Nn  = Bn * HW;            // 2097152 = 2^21
constexpr int N4  = Nn / 4;
constexpr int NB  = 15;                 // NBINS
constexpr int NQ  = 30;                 // rank queries per class
constexpr int NCHUNK = 32;              // chunks per class for hist/refine passes
constexpr int CHSZ = Nn / NCHUNK;       // 65536 elems per chunk

// ---------------------------------------------------------------------------
// Pass 1: softmax — pure streaming, NO atomics. Writes conf rows for group.
// ---------------------------------------------------------------------------
__global__ __launch_bounds__(256) void k_softmax(
    const float* __restrict__ lg, float* __restrict__ conf, int c0, int gc)
{
    int t = blockIdx.x * 256 + threadIdx.x;
    if (t >= N4) return;
    int n  = t * 4;
    int b  = n >> 19;
    int hw = n & (HW - 1);
    const float* base = lg + ((size_t)(b * Cn) << 19) + hw;

    float4 x[Cn];
#pragma unroll
    for (int c = 0; c < Cn; c++)
        x[c] = *reinterpret_cast<const float4*>(base + ((size_t)c << 19));

    float4 m = x[0];
#pragma unroll
    for (int c = 1; c < Cn; c++) {
        m.x = fmaxf(m.x, x[c].x); m.y = fmaxf(m.y, x[c].y);
        m.z = fmaxf(m.z, x[c].z); m.w = fmaxf(m.w, x[c].w);
    }
    float4 s = make_float4(0.f, 0.f, 0.f, 0.f);
#pragma unroll
    for (int c = 0; c < Cn; c++) {
        x[c].x = __expf(x[c].x - m.x); s.x += x[c].x;
        x[c].y = __expf(x[c].y - m.y); s.y += x[c].y;
        x[c].z = __expf(x[c].z - m.z); s.z += x[c].z;
        x[c].w = __expf(x[c].w - m.w); s.w += x[c].w;
    }
    float4 inv = make_float4(1.f / s.x, 1.f / s.y, 1.f / s.z, 1.f / s.w);

#pragma unroll
    for (int c = 0; c < Cn; c++) {
        if (c < c0 || c >= c0 + gc) continue;   // uniform predicate, x[] static-indexed
        float4 v;
        v.x = x[c].x * inv.x; v.y = x[c].y * inv.y;
        v.z = x[c].z * inv.z; v.w = x[c].w * inv.w;
        *reinterpret_cast<float4*>(conf + (size_t)(c - c0) * Nn + n) = v;
    }
}

// ---------------------------------------------------------------------------
// Pass 2: 12-bit (bits 31:20) LDS histogram, 4 replicas (one per wave),
// written as NON-atomic partial histograms per (class, chunk).
// ---------------------------------------------------------------------------
__global__ __launch_bounds__(256) void k_hist12(
    const float* __restrict__ conf, unsigned* __restrict__ partial)
{
    int cg = blockIdx.x >> 5, chunk = blockIdx.x & 31;
    int tid = threadIdx.x;
    __shared__ unsigned h[4 * 4096];
    for (int i = tid; i < 4 * 4096; i += 256) h[i] = 0;
    __syncthreads();
    unsigned* hr = h + ((tid >> 6) << 12);   // replica per wave

    const float4* p = reinterpret_cast<const float4*>(
        conf + (size_t)cg * Nn + (size_t)chunk * CHSZ);
    for (int it = 0; it < CHSZ / 1024; it++) {
        float4 v = p[it * 256 + tid];
        atomicAdd(&hr[__float_as_uint(v.x) >> 20], 1u);
        atomicAdd(&hr[__float_as_uint(v.y) >> 20], 1u);
        atomicAdd(&hr[__float_as_uint(v.z) >> 20], 1u);
        atomicAdd(&hr[__float_as_uint(v.w) >> 20], 1u);
    }
    __syncthreads();
    unsigned* out = partial + (((size_t)(cg * NCHUNK + chunk)) << 12);
    for (int i = tid; i < 4096; i += 256)
        out[i] = h[i] + h[4096 + i] + h[8192 + i] + h[12288 + i];
}

// Reduce partial hists over chunks -> hist[cls][4096]
__global__ void k_hred(const unsigned* __restrict__ partial,
                       unsigned* __restrict__ hist, int gc)
{
    int i = blockIdx.x * 256 + threadIdx.x;
    if (i >= (gc << 12)) return;
    int cg = i >> 12, bin = i & 4095;
    unsigned s = 0;
    for (int ch = 0; ch < NCHUNK; ch++)
        s += partial[(((size_t)(cg * NCHUNK + ch)) << 12) + bin];
    hist[i] = s;
}

// In-place inclusive scan of each class's 4096-bin histogram
__global__ __launch_bounds__(1024) void k_scan12(unsigned* __restrict__ hist)
{
    int cg = blockIdx.x, t = threadIdx.x;
    unsigned* c = hist + ((size_t)cg << 12);
    int base = t * 4;
    unsigned s = c[base] + c[base + 1] + c[base + 2] + c[base + 3];
    __shared__ unsigned ls[1024];
    ls[t] = s; __syncthreads();
    for (int off = 1; off < 1024; off <<= 1) {
        unsigned v = (t >= off) ? ls[t - off] : 0u;
        __syncthreads();
        ls[t] += v;
        __syncthreads();
    }
    unsigned run = ls[t] - s;
    for (int k = 0; k < 4; k++) { run += c[base + k]; c[base + k] = run; }
}

// rank of query slot s: 0 -> 0; 29 -> N-1; 2k-1 -> floor(k*N/15); 2k -> +1
__device__ __forceinline__ long long rank_of_slot(int s)
{
    if (s == 0)  return 0;
    if (s == 29) return (long long)Nn - 1;
    int k = (s & 1) ? ((s + 1) >> 1) : (s >> 1);
    double pos = (double)k * (double)Nn / 15.0;
    long long ik = (long long)floor(pos);
    return (s & 1) ? ik : ik + 1;
}

// ---------------------------------------------------------------------------
// Locate each rank's 12-bit bucket + residual rank; build sorted prefix list
// ---------------------------------------------------------------------------
__global__ void k_find12(const unsigned* __restrict__ hist,
                         unsigned* __restrict__ qprefix, unsigned* __restrict__ qresid,
                         unsigned* __restrict__ ulist, unsigned* __restrict__ uslot, int gc)
{
    int t = threadIdx.x, cg = t >> 5, q = t & 31;
    __shared__ unsigned sp[19 * 32];
    unsigned p = 0xFFFFFFFFu, resid = 0;
    bool active = (q < NQ);
    if (active) {
        long long r = rank_of_slot(q);
        const unsigned* c = hist + ((size_t)cg << 12);
        unsigned pos = 0;
#pragma unroll
        for (int st = 2048; st >= 1; st >>= 1) {
            unsigned np = pos + st;
            if (c[np - 1] <= (unsigned)r) pos = np;
        }
        unsigned prev = pos ? c[pos - 1] : 0u;
        p = pos; resid = (unsigned)r - prev;
    }
    sp[t] = p;
    __syncthreads();
    if (active) {
        const unsigned* row = sp + cg * 32;
        int rfull = 0, less = 0;
        for (int j = 0; j < NQ; j++) {
            unsigned pj = row[j];
            less  += (pj < p);
            rfull += (pj < p) || (pj == p && j < q);
        }
        qprefix[t] = p; qresid[t] = resid; uslot[t] = (unsigned)less;
        ulist[cg * 32 + rfull] = p;
    } else {
        ulist[cg * 32 + q] = 0xFFFFFFFFu;  // pad slots 30,31
    }
}

// ---------------------------------------------------------------------------
// Refinement levels. Element matches a known prefix; histogram next bits.
// L=0: key=bits>>20 (12b known), sym=(bits>>12)&255, 256 bins
// L=1: key=bits>>12 (20b known), sym=(bits>> 4)&255, 256 bins
// L=2: key=bits>> 4 (28b known), sym= bits     & 15,  16 bins
// ---------------------------------------------------------------------------
template <int L>
__global__ __launch_bounds__(256) void k_refine(
    const float* __restrict__ conf, const unsigned* __restrict__ ulist,
    unsigned* __restrict__ qhist)
{
    constexpr int BINS = (L == 2) ? 16 : 256;
    int cg = blockIdx.x >> 5, chunk = blockIdx.x & 31;
    int tid = threadIdx.x;
    __shared__ unsigned ul[32];
    __shared__ unsigned h[32 * BINS];
    for (int i = tid; i < 32 * BINS; i += 256) h[i] = 0;
    if (tid < 32) ul[tid] = ulist[cg * 32 + tid];
    __syncthreads();

    const float4* p = reinterpret_cast<const float4*>(
        conf + (size_t)cg * Nn + (size_t)chunk * CHSZ);
    for (int it = 0; it < CHSZ / 1024; it++) {
        float4 v = p[it * 256 + tid];
        unsigned bb[4] = { __float_as_uint(v.x), __float_as_uint(v.y),
                           __float_as_uint(v.z), __float_as_uint(v.w) };
#pragma unroll
        for (int j = 0; j < 4; j++) {
            unsigned bits = bb[j];
            unsigned key = (L == 0) ? (bits >> 20) : (L == 1) ? (bits >> 12) : (bits >> 4);
            unsigned sym = (L == 0) ? ((bits >> 12) & 255u)
                         : (L == 1) ? ((bits >> 4) & 255u) : (bits & 15u);
            unsigned pos = (ul[15] < key) ? 16u : 0u;     // branchless lower_bound(32)
            pos += (ul[pos + 7] < key) ? 8u : 0u;
            pos += (ul[pos + 3] < key) ? 4u : 0u;
            pos += (ul[pos + 1] < key) ? 2u : 0u;
            pos += (ul[pos]     < key) ? 1u : 0u;
            if (pos < 32u && ul[pos] == key)
                atomicAdd(&h[pos * BINS + sym], 1u);
        }
    }
    __syncthreads();
    for (int i = tid; i < 32 * BINS; i += 256) {
        unsigned v = h[i];
        if (v) atomicAdd(&qhist[(size_t)cg * 32 * BINS + i], v);
    }
}

// ---------------------------------------------------------------------------
// Scan per-query histograms; extend prefix; rebuild sorted list, or (final)
// produce edges.
// ---------------------------------------------------------------------------
template <int BINS, int SHIFT, int FINAL>
__global__ void k_scanq(const unsigned* __restrict__ qhist,
                        unsigned* __restrict__ qprefix, unsigned* __restrict__ qresid,
                        unsigned* __restrict__ uslot, unsigned* __restrict__ ulist_next,
                        float* __restrict__ edges, int c0)
{
    int t = threadIdx.x, cg = t >> 5, q = t & 31;
    bool active = (q < NQ);
    unsigned np = 0xFFFFFFFFu;
    if (active) {
        unsigned slot = uslot[t];
        unsigned r = qresid[t];
        const unsigned* hb = qhist + (size_t)cg * 32 * BINS + slot * BINS;
        unsigned cum = 0, sym = BINS - 1, nr = r;
        int found = 0;
        for (int b2 = 0; b2 < BINS; b2++) {
            unsigned cb = hb[b2];
            if (!found && r < cum + cb) { sym = (unsigned)b2; nr = r - cum; found = 1; }
            cum += cb;
        }
        np = (qprefix[t] << SHIFT) | sym;
        qresid[t] = nr;
        qprefix[t] = np;
    }
    if (!FINAL) {
        __shared__ unsigned sp[19 * 32];
        sp[t] = active ? np : 0xFFFFFFFFu;
        __syncthreads();
        if (active) {
            const unsigned* row = sp + cg * 32;
            int rfull = 0, less = 0;
            for (int j = 0; j < NQ; j++) {
                unsigned pj = row[j];
                less  += (pj < np);
                rfull += (pj < np) || (pj == np && j < q);
            }
            uslot[t] = (unsigned)less;
            ulist_next[cg * 32 + rfull] = np;
        } else {
            ulist_next[cg * 32 + q] = 0xFFFFFFFFu;
        }
    } else {
        __shared__ float sv[19 * 32];
        sv[t] = active ? __uint_as_float(np) : 0.f;
        __syncthreads();
        if (q < 16) {
            const float* vals = sv + cg * 32;
            float e;
            if (q == 0)       e = vals[0];
            else if (q == 15) e = vals[29];
            else {
                double pos = (double)q * (double)Nn / 15.0;
                double fr  = pos - floor(pos);
                float v0 = vals[2 * q - 1], v1 = vals[2 * q];
                e = v0 + (float)fr * (v1 - v0);
            }
            edges[(size_t)(c0 + cg) * 16 + q] = e;
        }
    }
}

// ---------------------------------------------------------------------------
// Binning + accumulation (count, sum_conf, sum_correct per class/bin)
// 2 LDS replicas (per wave-pair) to cut hot-bin serialization.
// ---------------------------------------------------------------------------
__global__ __launch_bounds__(256) void k_bin(
    const float* __restrict__ conf, const int* __restrict__ labels,
    const float* __restrict__ edges, float* __restrict__ accum, int c0, int gc)
{
    __shared__ float eL[19 * 16];
    __shared__ float acc[2][19 * 45];
    int tid = threadIdx.x;
    for (int i = tid; i < gc * 45; i += 256) { acc[0][i] = 0.f; acc[1][i] = 0.f; }
    for (int i = tid; i < gc * 16; i += 256) eL[i] = edges[(size_t)c0 * 16 + i];
    __syncthreads();
    float* ar = acc[(tid >> 6) & 1];

    int t = blockIdx.x * 256 + tid;
    if (t < N4) {
        int n = t * 4;
        int4 lab = *reinterpret_cast<const int4*>(labels + n);
        int lb[4] = { lab.x, lab.y, lab.z, lab.w };
        for (int cg = 0; cg < gc; cg++) {
            float4 v = *reinterpret_cast<const float4*>(conf + (size_t)cg * Nn + n);
            int c = c0 + cg;
            const float* e = eL + cg * 16;
            float vv[4] = { v.x, v.y, v.z, v.w };
#pragma unroll
            for (int j = 0; j < 4; j++) {
                int cnt = 0;
#pragma unroll
                for (int i = 0; i < 16; i++) cnt += (e[i] < vv[j]) ? 1 : 0;
                int idx = cnt - 1;                    // searchsorted(left) - 1
                if (idx >= 0 && idx < NB) {
                    float* a = ar + (cg * NB + idx) * 3;
                    atomicAdd(a, 1.f);
                    atomicAdd(a + 1, vv[j]);
                    if (lb[j] == c) atomicAdd(a + 2, 1.f);
                }
            }
        }
    }
    __syncthreads();
    for (int i = tid; i < gc * 45; i += 256) {
        float v = acc[0][i] + acc[1][i];
        if (v != 0.f) atomicAdd(&accum[(size_t)c0 * 45 + i], v);
    }
}

// ---------------------------------------------------------------------------
// Finalize: per-class aece + mean
// ---------------------------------------------------------------------------
__global__ void k_final(const float* __restrict__ accum, float* __restrict__ out)
{
    int c = threadIdx.x;
    __shared__ float pcs[Cn];
    if (c < Cn) {
        float pc = 0.f;
        for (int j = 0; j < NB; j++) {
            float cnt = accum[(c * NB + j) * 3];
            if (cnt > 0.f) {
                float sc  = accum[(c * NB + j) * 3 + 1];
                float scr = accum[(c * NB + j) * 3 + 2];
                float a   = scr / cnt;
                float avg = sc / cnt;
                float prop = cnt / (float)Nn;
                pc += fabsf(avg - a) * prop;
            }
        }
        pcs[c] = pc;
        out[1 + c] = pc;
    }
    __syncthreads();
    if (c == 0) {
        float s = 0.f;
        for (int j = 0; j < Cn; j++) s += pcs[j];
        out[0] = s / (float)Cn;
    }
}

// ---------------------------------------------------------------------------
extern "C" void kernel_launch(void* const* d_in, const int* in_sizes, int n_in,
                              void* d_out, int out_size, void* d_ws, size_t ws_size,
                              hipStream_t stream)
{
    const float* logits = (const float*)d_in[0];
    const int*   labels = (const int*)d_in[1];
    float* out = (float*)d_out;
    char*  ws  = (char*)d_ws;

    // Class-group sizing from available workspace
    size_t per_class = (size_t)Nn * 4                 // conf row
                     + (size_t)NCHUNK * 4096 * 4      // partial hists
                     + (size_t)4096 * 4               // merged hist
                     + 2ull * 32 * 256 * 4            // qhistA/B
                     + 32 * 16 * 4;                   // qhistC
    size_t fixed = 65536;
    int gc = (ws_size > fixed) ? (int)((ws_size - fixed) / per_class) : 1;
    if (gc > Cn) gc = Cn;
    if (gc < 1)  gc = 1;
    int ng = (Cn + gc - 1) / gc;

    size_t off = 0;
    auto alloc = [&](size_t bytes) { size_t o = off; off += (bytes + 255) & ~(size_t)255; return o; };
    float*    conf    = (float*)(ws + alloc((size_t)gc * Nn * 4));
    unsigned* partial = (unsigned*)(ws + alloc((size_t)gc * NCHUNK * 4096 * 4));
    unsigned* hist12  = (unsigned*)(ws + alloc((size_t)gc * 4096 * 4));
    unsigned* qhistA  = (unsigned*)(ws + alloc((size_t)gc * 32 * 256 * 4));
    unsigned* qhistB  = (unsigned*)(ws + alloc((size_t)gc * 32 * 256 * 4));
    unsigned* qhistC  = (unsigned*)(ws + alloc((size_t)gc * 32 * 16 * 4));
    unsigned* qprefix = (unsigned*)(ws + alloc(19 * 32 * 4));
    unsigned* qresid  = (unsigned*)(ws + alloc(19 * 32 * 4));
    unsigned* uslot   = (unsigned*)(ws + alloc(19 * 32 * 4));
    unsigned* ulist0  = (unsigned*)(ws + alloc(19 * 32 * 4));
    unsigned* ulist1  = (unsigned*)(ws + alloc(19 * 32 * 4));
    unsigned* ulist2  = (unsigned*)(ws + alloc(19 * 32 * 4));
    float*    edges   = (float*)(ws + alloc(19 * 16 * 4));
    float*    accum   = (float*)(ws + alloc(19 * 45 * 4));

    hipMemsetAsync(accum, 0, 19 * 45 * 4, stream);
    for (int g = 0; g < ng; g++) {
        int c0 = g * gc;
        int gcc = (Cn - c0 < gc) ? (Cn - c0) : gc;
        hipMemsetAsync(qhistA, 0, (size_t)gcc * 32 * 256 * 4, stream);
        hipMemsetAsync(qhistB, 0, (size_t)gcc * 32 * 256 * 4, stream);
        hipMemsetAsync(qhistC, 0, (size_t)gcc * 32 * 16 * 4, stream);

        k_softmax<<<N4 / 256, 256, 0, stream>>>(logits, conf, c0, gcc);
        k_hist12<<<gcc * NCHUNK, 256, 0, stream>>>(conf, partial);
        k_hred<<<(gcc * 4096 + 255) / 256, 256, 0, stream>>>(partial, hist12, gcc);
        k_scan12<<<gcc, 1024, 0, stream>>>(hist12);
        k_find12<<<1, gcc * 32, 0, stream>>>(hist12, qprefix, qresid, ulist0, uslot, gcc);
        k_refine<0><<<gcc * NCHUNK, 256, 0, stream>>>(conf, ulist0, qhistA);
        k_scanq<256, 8, 0><<<1, gcc * 32, 0, stream>>>(qhistA, qprefix, qresid, uslot,
                                                       ulist1, edges, c0);
        k_refine<1><<<gcc * NCHUNK, 256, 0, stream>>>(conf, ulist1, qhistB);
        k_scanq<256, 8, 0><<<1, gcc * 32, 0, stream>>>(qhistB, qprefix, qresid, uslot,
                                                       ulist2, edges, c0);
        k_refine<2><<<gcc * NCHUNK, 256, 0, stream>>>(conf, ulist2, qhistC);
        k_scanq<16, 4, 1><<<1, gcc * 32, 0, stream>>>(qhistC, qprefix, qresid, uslot,
                                                      ulist0, edges, c0);
        k_bin<<<N4 / 256, 256, 0, stream>>>(conf, labels, edges, accum, c0, gcc);
    }
    k_final<<<1, 64, 0, stream>>>(accum, out);
}

// Round 5
// 930.465 us; speedup vs baseline: 2.3537x; 1.2233x over previous
//
#include <hip/hip_runtime.h>
#include <cstdint>
#include <cmath>

// Problem constants (fixed by reference setup_inputs)
constexpr int Bn = 4, Cn = 19, Hn = 512, Wn = 1024;
constexpr int HW  = Hn * Wn;            // 524288 = 2^19
constexpr int Nn  = Bn * HW;            // 2097152 = 2^21
constexpr int N4  = Nn / 4;
constexpr int NB  = 15;                 // NBINS
constexpr int NQ  = 30;                 // rank queries per class
constexpr int NCHUNK = 32;              // chunks per class for hist/refine passes
constexpr int CHSZ = Nn / NCHUNK;       // 65536 elems per chunk

// ---------------------------------------------------------------------------
// Pass 1: softmax — pure streaming, NO atomics. Writes conf rows for group.
// ---------------------------------------------------------------------------
__global__ __launch_bounds__(256) void k_softmax(
    const float* __restrict__ lg, float* __restrict__ conf, int c0, int gc)
{
    int t = blockIdx.x * 256 + threadIdx.x;
    if (t >= N4) return;
    int n  = t * 4;
    int b  = n >> 19;
    int hw = n & (HW - 1);
    const float* base = lg + ((size_t)(b * Cn) << 19) + hw;

    float4 x[Cn];
#pragma unroll
    for (int c = 0; c < Cn; c++)
        x[c] = *reinterpret_cast<const float4*>(base + ((size_t)c << 19));

    float4 m = x[0];
#pragma unroll
    for (int c = 1; c < Cn; c++) {
        m.x = fmaxf(m.x, x[c].x); m.y = fmaxf(m.y, x[c].y);
        m.z = fmaxf(m.z, x[c].z); m.w = fmaxf(m.w, x[c].w);
    }
    float4 s = make_float4(0.f, 0.f, 0.f, 0.f);
#pragma unroll
    for (int c = 0; c < Cn; c++) {
        x[c].x = __expf(x[c].x - m.x); s.x += x[c].x;
        x[c].y = __expf(x[c].y - m.y); s.y += x[c].y;
        x[c].z = __expf(x[c].z - m.z); s.z += x[c].z;
        x[c].w = __expf(x[c].w - m.w); s.w += x[c].w;
    }
    float4 inv = make_float4(1.f / s.x, 1.f / s.y, 1.f / s.z, 1.f / s.w);

#pragma unroll
    for (int c = 0; c < Cn; c++) {
        if (c < c0 || c >= c0 + gc) continue;   // uniform predicate, x[] static-indexed
        float4 v;
        v.x = x[c].x * inv.x; v.y = x[c].y * inv.y;
        v.z = x[c].z * inv.z; v.w = x[c].w * inv.w;
        *reinterpret_cast<float4*>(conf + (size_t)(c - c0) * Nn + n) = v;
    }
}

// ---------------------------------------------------------------------------
// Pass 2: 12-bit (bits 31:20) LDS histogram, 4 replicas (one per wave),
// written as NON-atomic partial histograms per (class, chunk).
// ---------------------------------------------------------------------------
__global__ __launch_bounds__(256) void k_hist12(
    const float* __restrict__ conf, unsigned* __restrict__ partial)
{
    int cg = blockIdx.x >> 5, chunk = blockIdx.x & 31;
    int tid = threadIdx.x;
    __shared__ unsigned h[4 * 4096];
    for (int i = tid; i < 4 * 4096; i += 256) h[i] = 0;
    __syncthreads();
    unsigned* hr = h + ((tid >> 6) << 12);   // replica per wave

    const float4* p = reinterpret_cast<const float4*>(
        conf + (size_t)cg * Nn + (size_t)chunk * CHSZ);
    for (int it = 0; it < CHSZ / 1024; it++) {
        float4 v = p[it * 256 + tid];
        atomicAdd(&hr[__float_as_uint(v.x) >> 20], 1u);
        atomicAdd(&hr[__float_as_uint(v.y) >> 20], 1u);
        atomicAdd(&hr[__float_as_uint(v.z) >> 20], 1u);
        atomicAdd(&hr[__float_as_uint(v.w) >> 20], 1u);
    }
    __syncthreads();
    unsigned* out = partial + (((size_t)(cg * NCHUNK + chunk)) << 12);
    for (int i = tid; i < 4096; i += 256)
        out[i] = h[i] + h[4096 + i] + h[8192 + i] + h[12288 + i];
}

// Reduce partial hists over chunks -> hist[cls][4096]
__global__ void k_hred(const unsigned* __restrict__ partial,
                       unsigned* __restrict__ hist, int gc)
{
    int i = blockIdx.x * 256 + threadIdx.x;
    if (i >= (gc << 12)) return;
    int cg = i >> 12, bin = i & 4095;
    unsigned s = 0;
    for (int ch = 0; ch < NCHUNK; ch++)
        s += partial[(((size_t)(cg * NCHUNK + ch)) << 12) + bin];
    hist[i] = s;
}

// In-place inclusive scan of each class's 4096-bin histogram
__global__ __launch_bounds__(1024) void k_scan12(unsigned* __restrict__ hist)
{
    int cg = blockIdx.x, t = threadIdx.x;
    unsigned* c = hist + ((size_t)cg << 12);
    int base = t * 4;
    unsigned s = c[base] + c[base + 1] + c[base + 2] + c[base + 3];
    __shared__ unsigned ls[1024];
    ls[t] = s; __syncthreads();
    for (int off = 1; off < 1024; off <<= 1) {
        unsigned v = (t >= off) ? ls[t - off] : 0u;
        __syncthreads();
        ls[t] += v;
        __syncthreads();
    }
    unsigned run = ls[t] - s;
    for (int k = 0; k < 4; k++) { run += c[base + k]; c[base + k] = run; }
}

// rank of query slot s: 0 -> 0; 29 -> N-1; 2k-1 -> floor(k*N/15); 2k -> +1
__device__ __forceinline__ long long rank_of_slot(int s)
{
    if (s == 0)  return 0;
    if (s == 29) return (long long)Nn - 1;
    int k = (s & 1) ? ((s + 1) >> 1) : (s >> 1);
    double pos = (double)k * (double)Nn / 15.0;
    long long ik = (long long)floor(pos);
    return (s & 1) ? ik : ik + 1;
}

// ---------------------------------------------------------------------------
// Locate each rank's 12-bit bucket + residual rank; build sorted prefix list
// ---------------------------------------------------------------------------
__global__ void k_find12(const unsigned* __restrict__ hist,
                         unsigned* __restrict__ qprefix, unsigned* __restrict__ qresid,
                         unsigned* __restrict__ ulist, unsigned* __restrict__ uslot, int gc)
{
    int t = threadIdx.x, cg = t >> 5, q = t & 31;
    __shared__ unsigned sp[19 * 32];
    unsigned p = 0xFFFFFFFFu, resid = 0;
    bool active = (q < NQ);
    if (active) {
        long long r = rank_of_slot(q);
        const unsigned* c = hist + ((size_t)cg << 12);
        unsigned pos = 0;
#pragma unroll
        for (int st = 2048; st >= 1; st >>= 1) {
            unsigned np = pos + st;
            if (c[np - 1] <= (unsigned)r) pos = np;
        }
        unsigned prev = pos ? c[pos - 1] : 0u;
        p = pos; resid = (unsigned)r - prev;
    }
    sp[t] = p;
    __syncthreads();
    if (active) {
        const unsigned* row = sp + cg * 32;
        int rfull = 0, less = 0;
        for (int j = 0; j < NQ; j++) {
            unsigned pj = row[j];
            less  += (pj < p);
            rfull += (pj < p) || (pj == p && j < q);
        }
        qprefix[t] = p; qresid[t] = resid; uslot[t] = (unsigned)less;
        ulist[cg * 32 + rfull] = p;
    } else {
        ulist[cg * 32 + q] = 0xFFFFFFFFu;  // pad slots 30,31
    }
}

// ---------------------------------------------------------------------------
// Refinement levels. Element matches a known prefix; histogram next bits.
// L=0: key=bits>>20 (12b known), sym=(bits>>12)&255, 256 bins
// L=1: key=bits>>12 (20b known), sym=(bits>> 4)&255, 256 bins
// L=2: key=bits>> 4 (28b known), sym= bits     & 15,  16 bins
// ---------------------------------------------------------------------------
template <int L>
__global__ __launch_bounds__(256) void k_refine(
    const float* __restrict__ conf, const unsigned* __restrict__ ulist,
    unsigned* __restrict__ qhist)
{
    constexpr int BINS = (L == 2) ? 16 : 256;
    int cg = blockIdx.x >> 5, chunk = blockIdx.x & 31;
    int tid = threadIdx.x;
    __shared__ unsigned ul[32];
    __shared__ unsigned h[32 * BINS];
    for (int i = tid; i < 32 * BINS; i += 256) h[i] = 0;
    if (tid < 32) ul[tid] = ulist[cg * 32 + tid];
    __syncthreads();

    const float4* p = reinterpret_cast<const float4*>(
        conf + (size_t)cg * Nn + (size_t)chunk * CHSZ);
    for (int it = 0; it < CHSZ / 1024; it++) {
        float4 v = p[it * 256 + tid];
        unsigned bb[4] = { __float_as_uint(v.x), __float_as_uint(v.y),
                           __float_as_uint(v.z), __float_as_uint(v.w) };
#pragma unroll
        for (int j = 0; j < 4; j++) {
            unsigned bits = bb[j];
            unsigned key = (L == 0) ? (bits >> 20) : (L == 1) ? (bits >> 12) : (bits >> 4);
            unsigned sym = (L == 0) ? ((bits >> 12) & 255u)
                         : (L == 1) ? ((bits >> 4) & 255u) : (bits & 15u);
            unsigned pos = (ul[15] < key) ? 16u : 0u;     // branchless lower_bound(32)
            pos += (ul[pos + 7] < key) ? 8u : 0u;
            pos += (ul[pos + 3] < key) ? 4u : 0u;
            pos += (ul[pos + 1] < key) ? 2u : 0u;
            pos += (ul[pos]     < key) ? 1u : 0u;
            if (pos < 32u && ul[pos] == key)
                atomicAdd(&h[pos * BINS + sym], 1u);
        }
    }
    __syncthreads();
    for (int i = tid; i < 32 * BINS; i += 256) {
        unsigned v = h[i];
        if (v) atomicAdd(&qhist[(size_t)cg * 32 * BINS + i], v);
    }
}

// ---------------------------------------------------------------------------
// Scan per-query histograms; extend prefix; rebuild sorted list, or (final)
// produce edges.
// ---------------------------------------------------------------------------
template <int BINS, int SHIFT, int FINAL>
__global__ void k_scanq(const unsigned* __restrict__ qhist,
                        unsigned* __restrict__ qprefix, unsigned* __restrict__ qresid,
                        unsigned* __restrict__ uslot, unsigned* __restrict__ ulist_next,
                        float* __restrict__ edges, int c0)
{
    int t = threadIdx.x, cg = t >> 5, q = t & 31;
    bool active = (q < NQ);
    unsigned np = 0xFFFFFFFFu;
    if (active) {
        unsigned slot = uslot[t];
        unsigned r = qresid[t];
        const unsigned* hb = qhist + (size_t)cg * 32 * BINS + slot * BINS;
        unsigned cum = 0, sym = BINS - 1, nr = r;
        int found = 0;
        for (int b2 = 0; b2 < BINS; b2++) {
            unsigned cb = hb[b2];
            if (!found && r < cum + cb) { sym = (unsigned)b2; nr = r - cum; found = 1; }
            cum += cb;
        }
        np = (qprefix[t] << SHIFT) | sym;
        qresid[t] = nr;
        qprefix[t] = np;
    }
    if (!FINAL) {
        __shared__ unsigned sp[19 * 32];
        sp[t] = active ? np : 0xFFFFFFFFu;
        __syncthreads();
        if (active) {
            const unsigned* row = sp + cg * 32;
            int rfull = 0, less = 0;
            for (int j = 0; j < NQ; j++) {
                unsigned pj = row[j];
                less  += (pj < np);
                rfull += (pj < np) || (pj == np && j < q);
            }
            uslot[t] = (unsigned)less;
            ulist_next[cg * 32 + rfull] = np;
        } else {
            ulist_next[cg * 32 + q] = 0xFFFFFFFFu;
        }
    } else {
        __shared__ float sv[19 * 32];
        sv[t] = active ? __uint_as_float(np) : 0.f;
        __syncthreads();
        if (q < 16) {
            const float* vals = sv + cg * 32;
            float e;
            if (q == 0)       e = vals[0];
            else if (q == 15) e = vals[29];
            else {
                double pos = (double)q * (double)Nn / 15.0;
                double fr  = pos - floor(pos);
                float v0 = vals[2 * q - 1], v1 = vals[2 * q];
                e = v0 + (float)fr * (v1 - v0);
            }
            edges[(size_t)(c0 + cg) * 16 + q] = e;
        }
    }
}

// ---------------------------------------------------------------------------
// Binning + accumulation. Register accumulators (no atomics in hot loop):
// block = (class-in-group, chunk); each thread keeps cnt/sumconf/sumcorr for
// all 15 bins in registers (compile-time indexed), wave-reduces at the end.
// ---------------------------------------------------------------------------
__global__ __launch_bounds__(256) void k_bin(
    const float* __restrict__ conf, const int* __restrict__ labels,
    const float* __restrict__ edges, float* __restrict__ accum, int c0)
{
    int cgi   = blockIdx.x >> 5;       // class within group
    int chunk = blockIdx.x & 31;
    int tid   = threadIdx.x;
    int c     = c0 + cgi;

    float e[16];
#pragma unroll
    for (int i = 0; i < 16; i++) e[i] = edges[(size_t)c * 16 + i];  // uniform -> s-loads

    float cnt[NB], scf[NB], scr[NB];
#pragma unroll
    for (int b = 0; b < NB; b++) { cnt[b] = 0.f; scf[b] = 0.f; scr[b] = 0.f; }

    const float4* p  = reinterpret_cast<const float4*>(
        conf + (size_t)cgi * Nn + (size_t)chunk * CHSZ);
    const int4*   lp = reinterpret_cast<const int4*>(
        labels + (size_t)chunk * CHSZ);

    for (int it = 0; it < CHSZ / 1024; it++) {       // 64 iters
        float4 v  = p[it * 256 + tid];
        int4   lb = lp[it * 256 + tid];
        float vv[4] = { v.x, v.y, v.z, v.w };
        int   ll[4] = { lb.x, lb.y, lb.z, lb.w };
#pragma unroll
        for (int j = 0; j < 4; j++) {
            float x   = vv[j];
            bool corr = (ll[j] == c);
            bool g[16];
#pragma unroll
            for (int i = 0; i < 16; i++) g[i] = (e[i] < x);
#pragma unroll
            for (int b = 0; b < NB; b++) {
                bool in = g[b] && !g[b + 1];        // searchsorted(left)-1 == b
                cnt[b] += in ? 1.f : 0.f;
                scf[b] += in ? x   : 0.f;
                scr[b] += (in && corr) ? 1.f : 0.f;
            }
        }
    }

    // reduce: wave shuffle -> LDS -> 45 global atomics per block
    __shared__ float red[4][45];
    int lane = tid & 63, wv = tid >> 6;
#pragma unroll
    for (int b = 0; b < NB; b++) {
        float a0 = cnt[b], a1 = scf[b], a2 = scr[b];
        for (int off = 32; off; off >>= 1) {
            a0 += __shfl_down(a0, off);
            a1 += __shfl_down(a1, off);
            a2 += __shfl_down(a2, off);
        }
        if (lane == 0) {
            red[wv][b * 3]     = a0;
            red[wv][b * 3 + 1] = a1;
            red[wv][b * 3 + 2] = a2;
        }
    }
    __syncthreads();
    if (tid < 45) {
        float s = red[0][tid] + red[1][tid] + red[2][tid] + red[3][tid];
        if (s != 0.f) atomicAdd(&accum[(size_t)c * 45 + tid], s);
    }
}

// ---------------------------------------------------------------------------
// Finalize: per-class aece + mean
// ---------------------------------------------------------------------------
__global__ void k_final(const float* __restrict__ accum, float* __restrict__ out)
{
    int c = threadIdx.x;
    __shared__ float pcs[Cn];
    if (c < Cn) {
        float pc = 0.f;
        for (int j = 0; j < NB; j++) {
            float cnt = accum[(c * NB + j) * 3];
            if (cnt > 0.f) {
                float sc  = accum[(c * NB + j) * 3 + 1];
                float scr = accum[(c * NB + j) * 3 + 2];
                float a   = scr / cnt;
                float avg = sc / cnt;
                float prop = cnt / (float)Nn;
                pc += fabsf(avg - a) * prop;
            }
        }
        pcs[c] = pc;
        out[1 + c] = pc;
    }
    __syncthreads();
    if (c == 0) {
        float s = 0.f;
        for (int j = 0; j < Cn; j++) s += pcs[j];
        out[0] = s / (float)Cn;
    }
}

// ---------------------------------------------------------------------------
extern "C" void kernel_launch(void* const* d_in, const int* in_sizes, int n_in,
                              void* d_out, int out_size, void* d_ws, size_t ws_size,
                              hipStream_t stream)
{
    const float* logits = (const float*)d_in[0];
    const int*   labels = (const int*)d_in[1];
    float* out = (float*)d_out;
    char*  ws  = (char*)d_ws;

    // Class-group sizing from available workspace
    size_t per_class = (size_t)Nn * 4                 // conf row
                     + (size_t)NCHUNK * 4096 * 4      // partial hists
                     + (size_t)4096 * 4               // merged hist
                     + 2ull * 32 * 256 * 4            // qhistA/B
                     + 32 * 16 * 4;                   // qhistC
    size_t fixed = 65536;
    int gc = (ws_size > fixed) ? (int)((ws_size - fixed) / per_class) : 1;
    if (gc > Cn) gc = Cn;
    if (gc < 1)  gc = 1;
    int ng = (Cn + gc - 1) / gc;

    size_t off = 0;
    auto alloc = [&](size_t bytes) { size_t o = off; off += (bytes + 255) & ~(size_t)255; return o; };
    float*    conf    = (float*)(ws + alloc((size_t)gc * Nn * 4));
    unsigned* partial = (unsigned*)(ws + alloc((size_t)gc * NCHUNK * 4096 * 4));
    unsigned* hist12  = (unsigned*)(ws + alloc((size_t)gc * 4096 * 4));
    unsigned* qhistA  = (unsigned*)(ws + alloc((size_t)gc * 32 * 256 * 4));
    unsigned* qhistB  = (unsigned*)(ws + alloc((size_t)gc * 32 * 256 * 4));
    unsigned* qhistC  = (unsigned*)(ws + alloc((size_t)gc * 32 * 16 * 4));
    unsigned* qprefix = (unsigned*)(ws + alloc(19 * 32 * 4));
    unsigned* qresid  = (unsigned*)(ws + alloc(19 * 32 * 4));
    unsigned* uslot   = (unsigned*)(ws + alloc(19 * 32 * 4));
    unsigned* ulist0  = (unsigned*)(ws + alloc(19 * 32 * 4));
    unsigned* ulist1  = (unsigned*)(ws + alloc(19 * 32 * 4));
    unsigned* ulist2  = (unsigned*)(ws + alloc(19 * 32 * 4));
    float*    edges   = (float*)(ws + alloc(19 * 16 * 4));
    float*    accum   = (float*)(ws + alloc(19 * 45 * 4));

    hipMemsetAsync(accum, 0, 19 * 45 * 4, stream);
    for (int g = 0; g < ng; g++) {
        int c0 = g * gc;
        int gcc = (Cn - c0 < gc) ? (Cn - c0) : gc;
        hipMemsetAsync(qhistA, 0, (size_t)gcc * 32 * 256 * 4, stream);
        hipMemsetAsync(qhistB, 0, (size_t)gcc * 32 * 256 * 4, stream);
        hipMemsetAsync(qhistC, 0, (size_t)gcc * 32 * 16 * 4, stream);

        k_softmax<<<N4 / 256, 256, 0, stream>>>(logits, conf, c0, gcc);
        k_hist12<<<gcc * NCHUNK, 256, 0, stream>>>(conf, partial);
        k_hred<<<(gcc * 4096 + 255) / 256, 256, 0, stream>>>(partial, hist12, gcc);
        k_scan12<<<gcc, 1024, 0, stream>>>(hist12);
        k_find12<<<1, gcc * 32, 0, stream>>>(hist12, qprefix, qresid, ulist0, uslot, gcc);
        k_refine<0><<<gcc * NCHUNK, 256, 0, stream>>>(conf, ulist0, qhistA);
        k_scanq<256, 8, 0><<<1, gcc * 32, 0, stream>>>(qhistA, qprefix, qresid, uslot,
                                                       ulist1, edges, c0);
        k_refine<1><<<gcc * NCHUNK, 256, 0, stream>>>(conf, ulist1, qhistB);
        k_scanq<256, 8, 0><<<1, gcc * 32, 0, stream>>>(qhistB, qprefix, qresid, uslot,
                                                       ulist2, edges, c0);
        k_refine<2><<<gcc * NCHUNK, 256, 0, stream>>>(conf, ulist2, qhistC);
        k_scanq<16, 4, 1><<<1, gcc * 32, 0, stream>>>(qhistC, qprefix, qresid, uslot,
                                                      ulist0, edges, c0);
        k_bin<<<gcc * NCHUNK, 256, 0, stream>>>(conf, labels, edges, accum, c0);
    }
    k_final<<<1, 64, 0, stream>>>(accum, out);
}

// Round 7
// 789.439 us; speedup vs baseline: 2.7741x; 1.1786x over previous
//
#include <hip/hip_runtime.h>
#include <cstdint>
#include <cmath>

// Problem constants (fixed by reference setup_inputs)
constexpr int Bn = 4, Cn = 19, Hn = 512, Wn = 1024;
constexpr int HW  = Hn * Wn;            // 524288 = 2^19
constexpr int Nn  = Bn * HW;            // 2097152 = 2^21
constexpr int N4  = Nn / 4;
constexpr int NB  = 15;                 // NBINS
constexpr int NQ  = 30;                 // rank queries per class
constexpr int NCHUNK = 32;              // chunks per class for hist/refine passes
constexpr int CHSZ = Nn / NCHUNK;       // 65536 elems per chunk
constexpr int BCH  = 128;               // k_bin chunks per class (occupancy)
constexpr int BCHSZ = Nn / BCH;         // 16384 elems per k_bin chunk

// ---------------------------------------------------------------------------
// Pass 1: softmax — pure streaming, NO atomics. Writes conf rows for group.
// ---------------------------------------------------------------------------
__global__ __launch_bounds__(256) void k_softmax(
    const float* __restrict__ lg, float* __restrict__ conf, int c0, int gc)
{
    int t = blockIdx.x * 256 + threadIdx.x;
    if (t >= N4) return;
    int n  = t * 4;
    int b  = n >> 19;
    int hw = n & (HW - 1);
    const float* base = lg + ((size_t)(b * Cn) << 19) + hw;

    float4 x[Cn];
#pragma unroll
    for (int c = 0; c < Cn; c++)
        x[c] = *reinterpret_cast<const float4*>(base + ((size_t)c << 19));

    float4 m = x[0];
#pragma unroll
    for (int c = 1; c < Cn; c++) {
        m.x = fmaxf(m.x, x[c].x); m.y = fmaxf(m.y, x[c].y);
        m.z = fmaxf(m.z, x[c].z); m.w = fmaxf(m.w, x[c].w);
    }
    float4 s = make_float4(0.f, 0.f, 0.f, 0.f);
#pragma unroll
    for (int c = 0; c < Cn; c++) {
        x[c].x = __expf(x[c].x - m.x); s.x += x[c].x;
        x[c].y = __expf(x[c].y - m.y); s.y += x[c].y;
        x[c].z = __expf(x[c].z - m.z); s.z += x[c].z;
        x[c].w = __expf(x[c].w - m.w); s.w += x[c].w;
    }
    float4 inv = make_float4(1.f / s.x, 1.f / s.y, 1.f / s.z, 1.f / s.w);

#pragma unroll
    for (int c = 0; c < Cn; c++) {
        if (c < c0 || c >= c0 + gc) continue;   // uniform predicate, x[] static-indexed
        float4 v;
        v.x = x[c].x * inv.x; v.y = x[c].y * inv.y;
        v.z = x[c].z * inv.z; v.w = x[c].w * inv.w;
        *reinterpret_cast<float4*>(conf + (size_t)(c - c0) * Nn + n) = v;
    }
}

// ---------------------------------------------------------------------------
// Pass 2: 12-bit (bits 31:20) LDS histogram, 4 replicas (one per wave),
// written as NON-atomic partial histograms per (class, chunk).
// ---------------------------------------------------------------------------
__global__ __launch_bounds__(256) void k_hist12(
    const float* __restrict__ conf, unsigned* __restrict__ partial)
{
    int cg = blockIdx.x >> 5, chunk = blockIdx.x & 31;
    int tid = threadIdx.x;
    __shared__ unsigned h[4 * 4096];
    for (int i = tid; i < 4 * 4096; i += 256) h[i] = 0;
    __syncthreads();
    unsigned* hr = h + ((tid >> 6) << 12);   // replica per wave

    const float4* p = reinterpret_cast<const float4*>(
        conf + (size_t)cg * Nn + (size_t)chunk * CHSZ);
    for (int it = 0; it < CHSZ / 1024; it++) {
        float4 v = p[it * 256 + tid];
        atomicAdd(&hr[__float_as_uint(v.x) >> 20], 1u);
        atomicAdd(&hr[__float_as_uint(v.y) >> 20], 1u);
        atomicAdd(&hr[__float_as_uint(v.z) >> 20], 1u);
        atomicAdd(&hr[__float_as_uint(v.w) >> 20], 1u);
    }
    __syncthreads();
    unsigned* out = partial + (((size_t)(cg * NCHUNK + chunk)) << 12);
    for (int i = tid; i < 4096; i += 256)
        out[i] = h[i] + h[4096 + i] + h[8192 + i] + h[12288 + i];
}

// Reduce partial hists over chunks -> hist[cls][4096]
__global__ void k_hred(const unsigned* __restrict__ partial,
                       unsigned* __restrict__ hist, int gc)
{
    int i = blockIdx.x * 256 + threadIdx.x;
    if (i >= (gc << 12)) return;
    int cg = i >> 12, bin = i & 4095;
    unsigned s = 0;
    for (int ch = 0; ch < NCHUNK; ch++)
        s += partial[(((size_t)(cg * NCHUNK + ch)) << 12) + bin];
    hist[i] = s;
}

// In-place inclusive scan of each class's 4096-bin histogram
__global__ __launch_bounds__(1024) void k_scan12(unsigned* __restrict__ hist)
{
    int cg = blockIdx.x, t = threadIdx.x;
    unsigned* c = hist + ((size_t)cg << 12);
    int base = t * 4;
    unsigned s = c[base] + c[base + 1] + c[base + 2] + c[base + 3];
    __shared__ unsigned ls[1024];
    ls[t] = s; __syncthreads();
    for (int off = 1; off < 1024; off <<= 1) {
        unsigned v = (t >= off) ? ls[t - off] : 0u;
        __syncthreads();
        ls[t] += v;
        __syncthreads();
    }
    unsigned run = ls[t] - s;
    for (int k = 0; k < 4; k++) { run += c[base + k]; c[base + k] = run; }
}

// rank of query slot s: 0 -> 0; 29 -> N-1; 2k-1 -> floor(k*N/15); 2k -> +1
__device__ __forceinline__ long long rank_of_slot(int s)
{
    if (s == 0)  return 0;
    if (s == 29) return (long long)Nn - 1;
    int k = (s & 1) ? ((s + 1) >> 1) : (s >> 1);
    double pos = (double)k * (double)Nn / 15.0;
    long long ik = (long long)floor(pos);
    return (s & 1) ? ik : ik + 1;
}

// ---------------------------------------------------------------------------
// Locate each rank's 12-bit bucket + residual rank; build sorted prefix list
// ---------------------------------------------------------------------------
__global__ void k_find12(const unsigned* __restrict__ hist,
                         unsigned* __restrict__ qprefix, unsigned* __restrict__ qresid,
                         unsigned* __restrict__ ulist, unsigned* __restrict__ uslot, int gc)
{
    int t = threadIdx.x, cg = t >> 5, q = t & 31;
    __shared__ unsigned sp[19 * 32];
    unsigned p = 0xFFFFFFFFu, resid = 0;
    bool active = (q < NQ);
    if (active) {
        long long r = rank_of_slot(q);
        const unsigned* c = hist + ((size_t)cg << 12);
        unsigned pos = 0;
#pragma unroll
        for (int st = 2048; st >= 1; st >>= 1) {
            unsigned np = pos + st;
            if (c[np - 1] <= (unsigned)r) pos = np;
        }
        unsigned prev = pos ? c[pos - 1] : 0u;
        p = pos; resid = (unsigned)r - prev;
    }
    sp[t] = p;
    __syncthreads();
    if (active) {
        const unsigned* row = sp + cg * 32;
        int rfull = 0, less = 0;
        for (int j = 0; j < NQ; j++) {
            unsigned pj = row[j];
            less  += (pj < p);
            rfull += (pj < p) || (pj == p && j < q);
        }
        qprefix[t] = p; qresid[t] = resid; uslot[t] = (unsigned)less;
        ulist[cg * 32 + rfull] = p;
    } else {
        ulist[cg * 32 + q] = 0xFFFFFFFFu;  // pad slots 30,31
    }
}

// ---------------------------------------------------------------------------
// Refinement levels. Element matches a known prefix; histogram next bits.
// L=0: key=bits>>20 (12b known), sym=(bits>>12)&255, 256 bins
// L=1: key=bits>>12 (20b known), sym=(bits>> 4)&255, 256 bins
// L=2: key=bits>> 4 (28b known), sym= bits     & 15,  16 bins
// ---------------------------------------------------------------------------
template <int L>
__global__ __launch_bounds__(256) void k_refine(
    const float* __restrict__ conf, const unsigned* __restrict__ ulist,
    unsigned* __restrict__ qhist)
{
    constexpr int BINS = (L == 2) ? 16 : 256;
    int cg = blockIdx.x >> 5, chunk = blockIdx.x & 31;
    int tid = threadIdx.x;
    __shared__ unsigned ul[32];
    __shared__ unsigned h[32 * BINS];
    for (int i = tid; i < 32 * BINS; i += 256) h[i] = 0;
    if (tid < 32) ul[tid] = ulist[cg * 32 + tid];
    __syncthreads();

    const float4* p = reinterpret_cast<const float4*>(
        conf + (size_t)cg * Nn + (size_t)chunk * CHSZ);
    for (int it = 0; it < CHSZ / 1024; it++) {
        float4 v = p[it * 256 + tid];
        unsigned bb[4] = { __float_as_uint(v.x), __float_as_uint(v.y),
                           __float_as_uint(v.z), __float_as_uint(v.w) };
#pragma unroll
        for (int j = 0; j < 4; j++) {
            unsigned bits = bb[j];
            unsigned key = (L == 0) ? (bits >> 20) : (L == 1) ? (bits >> 12) : (bits >> 4);
            unsigned sym = (L == 0) ? ((bits >> 12) & 255u)
                         : (L == 1) ? ((bits >> 4) & 255u) : (bits & 15u);
            unsigned pos = (ul[15] < key) ? 16u : 0u;     // branchless lower_bound(32)
            pos += (ul[pos + 7] < key) ? 8u : 0u;
            pos += (ul[pos + 3] < key) ? 4u : 0u;
            pos += (ul[pos + 1] < key) ? 2u : 0u;
            pos += (ul[pos]     < key) ? 1u : 0u;
            if (pos < 32u && ul[pos] == key)
                atomicAdd(&h[pos * BINS + sym], 1u);
        }
    }
    __syncthreads();
    for (int i = tid; i < 32 * BINS; i += 256) {
        unsigned v = h[i];
        if (v) atomicAdd(&qhist[(size_t)cg * 32 * BINS + i], v);
    }
}

// ---------------------------------------------------------------------------
// Scan per-query histograms; extend prefix; rebuild sorted list, or (final)
// produce edges.
// ---------------------------------------------------------------------------
template <int BINS, int SHIFT, int FINAL>
__global__ void k_scanq(const unsigned* __restrict__ qhist,
                        unsigned* __restrict__ qprefix, unsigned* __restrict__ qresid,
                        unsigned* __restrict__ uslot, unsigned* __restrict__ ulist_next,
                        float* __restrict__ edges, int c0)
{
    int t = threadIdx.x, cg = t >> 5, q = t & 31;
    bool active = (q < NQ);
    unsigned np = 0xFFFFFFFFu;
    if (active) {
        unsigned slot = uslot[t];
        unsigned r = qresid[t];
        const unsigned* hb = qhist + (size_t)cg * 32 * BINS + slot * BINS;
        unsigned cum = 0, sym = BINS - 1, nr = r;
        int found = 0;
        for (int b2 = 0; b2 < BINS; b2++) {
            unsigned cb = hb[b2];
            if (!found && r < cum + cb) { sym = (unsigned)b2; nr = r - cum; found = 1; }
            cum += cb;
        }
        np = (qprefix[t] << SHIFT) | sym;
        qresid[t] = nr;
        qprefix[t] = np;
    }
    if (!FINAL) {
        __shared__ unsigned sp[19 * 32];
        sp[t] = active ? np : 0xFFFFFFFFu;
        __syncthreads();
        if (active) {
            const unsigned* row = sp + cg * 32;
            int rfull = 0, less = 0;
            for (int j = 0; j < NQ; j++) {
                unsigned pj = row[j];
                less  += (pj < np);
                rfull += (pj < np) || (pj == np && j < q);
            }
            uslot[t] = (unsigned)less;
            ulist_next[cg * 32 + rfull] = np;
        } else {
            ulist_next[cg * 32 + q] = 0xFFFFFFFFu;
        }
    } else {
        __shared__ float sv[19 * 32];
        sv[t] = active ? __uint_as_float(np) : 0.f;
        __syncthreads();
        if (q < 16) {
            const float* vals = sv + cg * 32;
            float e;
            if (q == 0)       e = vals[0];
            else if (q == 15) e = vals[29];
            else {
                double pos = (double)q * (double)Nn / 15.0;
                double fr  = pos - floor(pos);
                float v0 = vals[2 * q - 1], v1 = vals[2 * q];
                e = v0 + (float)fr * (v1 - v0);
            }
            edges[(size_t)(c0 + cg) * 16 + q] = e;
        }
    }
}

// ---------------------------------------------------------------------------
// Binning + accumulation. Suffix-sum register accumulators:
// per edge i: gm = (e[i] < x);  C[i]+=gm;  S[i]=fma(gm,x);  R[i]=fma(gm,corr).
// Bin b values are suffix differences [b]-[b+1], taken per-thread (counts
// <= 64 per thread -> cnt/corr diffs exact). Grid 128 chunks/class for
// occupancy. Semantics identical: bin b iff e[b] < x AND NOT e[b+1] < x.
// ---------------------------------------------------------------------------
__global__ __launch_bounds__(256) void k_bin(
    const float* __restrict__ conf, const int* __restrict__ labels,
    const float* __restrict__ edges, float* __restrict__ accum, int c0)
{
    int cgi   = blockIdx.x >> 7;       // class within group (BCH=128)
    int chunk = blockIdx.x & (BCH - 1);
    int tid   = threadIdx.x;
    int c     = c0 + cgi;

    float e[16];
#pragma unroll
    for (int i = 0; i < 16; i++) e[i] = edges[(size_t)c * 16 + i];  // uniform -> s-loads

    float C[16], S[16], R[16];
#pragma unroll
    for (int i = 0; i < 16; i++) { C[i] = 0.f; S[i] = 0.f; R[i] = 0.f; }

    const float4* p  = reinterpret_cast<const float4*>(
        conf + (size_t)cgi * Nn + (size_t)chunk * BCHSZ);
    const int4*   lp = reinterpret_cast<const int4*>(
        labels + (size_t)chunk * BCHSZ);

    for (int it = 0; it < BCHSZ / 1024; it++) {      // 16 iters
        float4 v  = p[it * 256 + tid];
        int4   lb = lp[it * 256 + tid];
        float vv[4] = { v.x, v.y, v.z, v.w };
        int   ll[4] = { lb.x, lb.y, lb.z, lb.w };
#pragma unroll
        for (int j = 0; j < 4; j++) {
            float x     = vv[j];
            float corrf = (ll[j] == c) ? 1.f : 0.f;
#pragma unroll
            for (int i = 0; i < 16; i++) {
                float gm = (e[i] < x) ? 1.f : 0.f;
                C[i] += gm;
                S[i] = fmaf(gm, x,     S[i]);
                R[i] = fmaf(gm, corrf, R[i]);
            }
        }
    }

    // per-thread suffix -> bin diffs, wave shuffle reduce, 45 atomics/block
    __shared__ float red[4][45];
    int lane = tid & 63, wv = tid >> 6;
#pragma unroll
    for (int b = 0; b < NB; b++) {
        float a0 = C[b] - C[b + 1];
        float a1 = S[b] - S[b + 1];
        float a2 = R[b] - R[b + 1];
        for (int off = 32; off; off >>= 1) {
            a0 += __shfl_down(a0, off);
            a1 += __shfl_down(a1, off);
            a2 += __shfl_down(a2, off);
        }
        if (lane == 0) {
            red[wv][b * 3]     = a0;
            red[wv][b * 3 + 1] = a1;
            red[wv][b * 3 + 2] = a2;
        }
    }
    __syncthreads();
    if (tid < 45) {
        float s = red[0][tid] + red[1][tid] + red[2][tid] + red[3][tid];
        if (s != 0.f) atomicAdd(&accum[(size_t)c * 45 + tid], s);
    }
}

// ---------------------------------------------------------------------------
// Finalize: per-class aece + mean
// ---------------------------------------------------------------------------
__global__ void k_final(const float* __restrict__ accum, float* __restrict__ out)
{
    int c = threadIdx.x;
    __shared__ float pcs[Cn];
    if (c < Cn) {
        float pc = 0.f;
        for (int j = 0; j < NB; j++) {
            float cnt = accum[(c * NB + j) * 3];
            if (cnt > 0.f) {
                float sc  = accum[(c * NB + j) * 3 + 1];
                float scr = accum[(c * NB + j) * 3 + 2];
                float a   = scr / cnt;
                float avg = sc / cnt;
                float prop = cnt / (float)Nn;
                pc += fabsf(avg - a) * prop;
            }
        }
        pcs[c] = pc;
        out[1 + c] = pc;
    }
    __syncthreads();
    if (c == 0) {
        float s = 0.f;
        for (int j = 0; j < Cn; j++) s += pcs[j];
        out[0] = s / (float)Cn;
    }
}

// ---------------------------------------------------------------------------
extern "C" void kernel_launch(void* const* d_in, const int* in_sizes, int n_in,
                              void* d_out, int out_size, void* d_ws, size_t ws_size,
                              hipStream_t stream)
{
    const float* logits = (const float*)d_in[0];
    const int*   labels = (const int*)d_in[1];
    float* out = (float*)d_out;
    char*  ws  = (char*)d_ws;

    // Class-group sizing from available workspace
    size_t per_class = (size_t)Nn * 4                 // conf row
                     + (size_t)NCHUNK * 4096 * 4      // partial hists
                     + (size_t)4096 * 4               // merged hist
                     + 2ull * 32 * 256 * 4            // qhistA/B
                     + 32 * 16 * 4;                   // qhistC
    size_t fixed = 65536;
    int gc = (ws_size > fixed) ? (int)((ws_size - fixed) / per_class) : 1;
    if (gc > Cn) gc = Cn;
    if (gc < 1)  gc = 1;
    int ng = (Cn + gc - 1) / gc;

    size_t off = 0;
    auto alloc = [&](size_t bytes) { size_t o = off; off += (bytes + 255) & ~(size_t)255; return o; };
    float*    conf    = (float*)(ws + alloc((size_t)gc * Nn * 4));
    unsigned* partial = (unsigned*)(ws + alloc((size_t)gc * NCHUNK * 4096 * 4));
    unsigned* hist12  = (unsigned*)(ws + alloc((size_t)gc * 4096 * 4));
    unsigned* qhistA  = (unsigned*)(ws + alloc((size_t)gc * 32 * 256 * 4));
    unsigned* qhistB  = (unsigned*)(ws + alloc((size_t)gc * 32 * 256 * 4));
    unsigned* qhistC  = (unsigned*)(ws + alloc((size_t)gc * 32 * 16 * 4));
    unsigned* qprefix = (unsigned*)(ws + alloc(19 * 32 * 4));
    unsigned* qresid  = (unsigned*)(ws + alloc(19 * 32 * 4));
    unsigned* uslot   = (unsigned*)(ws + alloc(19 * 32 * 4));
    unsigned* ulist0  = (unsigned*)(ws + alloc(19 * 32 * 4));
    unsigned* ulist1  = (unsigned*)(ws + alloc(19 * 32 * 4));
    unsigned* ulist2  = (unsigned*)(ws + alloc(19 * 32 * 4));
    float*    edges   = (float*)(ws + alloc(19 * 16 * 4));
    float*    accum   = (float*)(ws + alloc(19 * 45 * 4));

    hipMemsetAsync(accum, 0, 19 * 45 * 4, stream);
    for (int g = 0; g < ng; g++) {
        int c0 = g * gc;
        int gcc = (Cn - c0 < gc) ? (Cn - c0) : gc;
        hipMemsetAsync(qhistA, 0, (size_t)gcc * 32 * 256 * 4, stream);
        hipMemsetAsync(qhistB, 0, (size_t)gcc * 32 * 256 * 4, stream);
        hipMemsetAsync(qhistC, 0, (size_t)gcc * 32 * 16 * 4, stream);

        k_softmax<<<N4 / 256, 256, 0, stream>>>(logits, conf, c0, gcc);
        k_hist12<<<gcc * NCHUNK, 256, 0, stream>>>(conf, partial);
        k_hred<<<(gcc * 4096 + 255) / 256, 256, 0, stream>>>(partial, hist12, gcc);
        k_scan12<<<gcc, 1024, 0, stream>>>(hist12);
        k_find12<<<1, gcc * 32, 0, stream>>>(hist12, qprefix, qresid, ulist0, uslot, gcc);
        k_refine<0><<<gcc * NCHUNK, 256, 0, stream>>>(conf, ulist0, qhistA);
        k_scanq<256, 8, 0><<<1, gcc * 32, 0, stream>>>(qhistA, qprefix, qresid, uslot,
                                                       ulist1, edges, c0);
        k_refine<1><<<gcc * NCHUNK, 256, 0, stream>>>(conf, ulist1, qhistB);
        k_scanq<256, 8, 0><<<1, gcc * 32, 0, stream>>>(qhistB, qprefix, qresid, uslot,
                                                       ulist2, edges, c0);
        k_refine<2><<<gcc * NCHUNK, 256, 0, stream>>>(conf, ulist2, qhistC);
        k_scanq<16, 4, 1><<<1, gcc * 32, 0, stream>>>(qhistC, qprefix, qresid, uslot,
                                                      ulist0, edges, c0);
        k_bin<<<gcc * BCH, 256, 0, stream>>>(conf, labels, edges, accum, c0);
    }
    k_final<<<1, 64, 0, stream>>>(accum, out);
}

// Round 8
// 770.652 us; speedup vs baseline: 2.8417x; 1.0244x over previous
//
#include <hip/hip_runtime.h>
#include <cstdint>
#include <cmath>

// Problem constants (fixed by reference setup_inputs)
constexpr int Bn = 4, Cn = 19, Hn = 512, Wn = 1024;
constexpr int HW  = Hn * Wn;            // 524288 = 2^19
constexpr int Nn  = Bn * HW;            // 2097152 = 2^21
constexpr int N8  = Nn / 8;
constexpr int NB  = 15;                 // NBINS
constexpr int NQ  = 30;                 // rank queries per class
constexpr int NCHUNK = 32;              // chunks per class for hist/refine passes
constexpr int CHSZ = Nn / NCHUNK;       // 65536 elems per chunk
constexpr int BCH  = 128;               // k_bin chunks per class (occupancy)
constexpr int BCHSZ = Nn / BCH;         // 16384 elems per k_bin chunk

// ---------------------------------------------------------------------------
// Pass 1: softmax — pure streaming, NO atomics. 8 elems/thread for MLP depth
// (was 4: latency-bound at 2.6 TB/s, VALUBusy 7%).
// ---------------------------------------------------------------------------
__global__ __launch_bounds__(256) void k_softmax(
    const float* __restrict__ lg, float* __restrict__ conf, int c0, int gc)
{
    int t = blockIdx.x * 256 + threadIdx.x;
    if (t >= N8) return;
    int n  = t * 8;
    int b  = n >> 19;
    int hw = n & (HW - 1);
    const float* base = lg + ((size_t)(b * Cn) << 19) + hw;

    float4 xa[Cn], xb[Cn];
#pragma unroll
    for (int c = 0; c < Cn; c++) {
        xa[c] = *reinterpret_cast<const float4*>(base + ((size_t)c << 19));
        xb[c] = *reinterpret_cast<const float4*>(base + ((size_t)c << 19) + 4);
    }

    float4 ma = xa[0], mb = xb[0];
#pragma unroll
    for (int c = 1; c < Cn; c++) {
        ma.x = fmaxf(ma.x, xa[c].x); ma.y = fmaxf(ma.y, xa[c].y);
        ma.z = fmaxf(ma.z, xa[c].z); ma.w = fmaxf(ma.w, xa[c].w);
        mb.x = fmaxf(mb.x, xb[c].x); mb.y = fmaxf(mb.y, xb[c].y);
        mb.z = fmaxf(mb.z, xb[c].z); mb.w = fmaxf(mb.w, xb[c].w);
    }
    float4 sa = make_float4(0.f, 0.f, 0.f, 0.f);
    float4 sb = make_float4(0.f, 0.f, 0.f, 0.f);
#pragma unroll
    for (int c = 0; c < Cn; c++) {
        xa[c].x = __expf(xa[c].x - ma.x); sa.x += xa[c].x;
        xa[c].y = __expf(xa[c].y - ma.y); sa.y += xa[c].y;
        xa[c].z = __expf(xa[c].z - ma.z); sa.z += xa[c].z;
        xa[c].w = __expf(xa[c].w - ma.w); sa.w += xa[c].w;
        xb[c].x = __expf(xb[c].x - mb.x); sb.x += xb[c].x;
        xb[c].y = __expf(xb[c].y - mb.y); sb.y += xb[c].y;
        xb[c].z = __expf(xb[c].z - mb.z); sb.z += xb[c].z;
        xb[c].w = __expf(xb[c].w - mb.w); sb.w += xb[c].w;
    }
    float4 ia = make_float4(1.f / sa.x, 1.f / sa.y, 1.f / sa.z, 1.f / sa.w);
    float4 ib = make_float4(1.f / sb.x, 1.f / sb.y, 1.f / sb.z, 1.f / sb.w);

#pragma unroll
    for (int c = 0; c < Cn; c++) {
        if (c < c0 || c >= c0 + gc) continue;   // uniform predicate, static idx
        float4 va, vb;
        va.x = xa[c].x * ia.x; va.y = xa[c].y * ia.y;
        va.z = xa[c].z * ia.z; va.w = xa[c].w * ia.w;
        vb.x = xb[c].x * ib.x; vb.y = xb[c].y * ib.y;
        vb.z = xb[c].z * ib.z; vb.w = xb[c].w * ib.w;
        float* dst = conf + (size_t)(c - c0) * Nn + n;
        *reinterpret_cast<float4*>(dst)     = va;
        *reinterpret_cast<float4*>(dst + 4) = vb;
    }
}

// ---------------------------------------------------------------------------
// Pass 2: 12-bit (bits 31:20) LDS histogram, 4 replicas (one per wave),
// written as NON-atomic partial histograms per (class, chunk).
// ---------------------------------------------------------------------------
__global__ __launch_bounds__(256) void k_hist12(
    const float* __restrict__ conf, unsigned* __restrict__ partial)
{
    int cg = blockIdx.x >> 5, chunk = blockIdx.x & 31;
    int tid = threadIdx.x;
    __shared__ unsigned h[4 * 4096];
    for (int i = tid; i < 4 * 4096; i += 256) h[i] = 0;
    __syncthreads();
    unsigned* hr = h + ((tid >> 6) << 12);   // replica per wave

    const float4* p = reinterpret_cast<const float4*>(
        conf + (size_t)cg * Nn + (size_t)chunk * CHSZ);
    for (int it = 0; it < CHSZ / 1024; it++) {
        float4 v = p[it * 256 + tid];
        atomicAdd(&hr[__float_as_uint(v.x) >> 20], 1u);
        atomicAdd(&hr[__float_as_uint(v.y) >> 20], 1u);
        atomicAdd(&hr[__float_as_uint(v.z) >> 20], 1u);
        atomicAdd(&hr[__float_as_uint(v.w) >> 20], 1u);
    }
    __syncthreads();
    unsigned* out = partial + (((size_t)(cg * NCHUNK + chunk)) << 12);
    for (int i = tid; i < 4096; i += 256)
        out[i] = h[i] + h[4096 + i] + h[8192 + i] + h[12288 + i];
}

// rank of query slot s: 0 -> 0; 29 -> N-1; 2k-1 -> floor(k*N/15); 2k -> +1
__device__ __forceinline__ long long rank_of_slot(int s)
{
    if (s == 0)  return 0;
    if (s == 29) return (long long)Nn - 1;
    int k = (s & 1) ? ((s + 1) >> 1) : (s >> 1);
    double pos = (double)k * (double)Nn / 15.0;
    long long ik = (long long)floor(pos);
    return (s & 1) ? ik : ik + 1;
}

// ---------------------------------------------------------------------------
// Merged hred + scan + find: one block per class (1024 threads).
// Reduces partials -> scans 4096 bins in LDS -> 30 rank queries -> ulist0.
// ---------------------------------------------------------------------------
__global__ __launch_bounds__(1024) void k_prep(
    const unsigned* __restrict__ partial,
    unsigned* __restrict__ qprefix, unsigned* __restrict__ qresid,
    unsigned* __restrict__ ulist0, unsigned* __restrict__ uslot)
{
    int cg = blockIdx.x, t = threadIdx.x;
    __shared__ unsigned cum[4096];
    __shared__ unsigned ls[1024];
    __shared__ unsigned sp[32];

    // phase 1: reduce 32 chunk-partials for my 4 bins
    int base = t * 4;
    unsigned b0 = 0, b1 = 0, b2 = 0, b3 = 0;
    for (int ch = 0; ch < NCHUNK; ch++) {
        const unsigned* pp = partial + (((size_t)(cg * NCHUNK + ch)) << 12) + base;
        b0 += pp[0]; b1 += pp[1]; b2 += pp[2]; b3 += pp[3];
    }
    unsigned s = b0 + b1 + b2 + b3;
    ls[t] = s; __syncthreads();
    for (int off = 1; off < 1024; off <<= 1) {
        unsigned v = (t >= off) ? ls[t - off] : 0u;
        __syncthreads();
        ls[t] += v;
        __syncthreads();
    }
    unsigned run = ls[t] - s;
    run += b0; cum[base]     = run;
    run += b1; cum[base + 1] = run;
    run += b2; cum[base + 2] = run;
    run += b3; cum[base + 3] = run;
    __syncthreads();

    // phase 2: 30 rank queries (threads 0..29)
    unsigned p = 0xFFFFFFFFu, resid = 0;
    if (t < NQ) {
        long long r = rank_of_slot(t);
        unsigned pos = 0;
#pragma unroll
        for (int st = 2048; st >= 1; st >>= 1) {
            unsigned np = pos + st;
            if (cum[np - 1] <= (unsigned)r) pos = np;
        }
        unsigned prev = pos ? cum[pos - 1] : 0u;
        p = pos; resid = (unsigned)r - prev;
    }
    if (t < 32) sp[t] = p;
    __syncthreads();
    if (t < NQ) {
        int rfull = 0, less = 0;
        for (int j = 0; j < NQ; j++) {
            unsigned pj = sp[j];
            less  += (pj < p);
            rfull += (pj < p) || (pj == p && j < t);
        }
        qprefix[cg * 32 + t] = p;
        qresid[cg * 32 + t]  = resid;
        uslot[cg * 32 + t]   = (unsigned)less;
        ulist0[cg * 32 + rfull] = p;
    } else if (t < 32) {
        ulist0[cg * 32 + t] = 0xFFFFFFFFu;   // pad slots 30,31
    }
}

__device__ __forceinline__ unsigned lb32(const unsigned* ul, unsigned key)
{
    unsigned pos = (ul[15] < key) ? 16u : 0u;
    pos += (ul[pos + 7] < key) ? 8u : 0u;
    pos += (ul[pos + 3] < key) ? 4u : 0u;
    pos += (ul[pos + 1] < key) ? 2u : 0u;
    pos += (ul[pos]     < key) ? 1u : 0u;
    return pos;
}

// ---------------------------------------------------------------------------
// Refine L0 on conf + COMPACTION: elements matching a 12-bit query bucket are
// appended (wave-ballot) to per-(class,chunk) segments as (pos<<20)|low20bits.
// Also histograms bits[19:12] per first-occurrence slot.
// ---------------------------------------------------------------------------
__global__ __launch_bounds__(256) void k_refine0(
    const float* __restrict__ conf, const unsigned* __restrict__ ulist0,
    unsigned* __restrict__ qhistA, unsigned* __restrict__ cbuf,
    unsigned* __restrict__ counts)
{
    int cg = blockIdx.x >> 5, chunk = blockIdx.x & 31;
    int tid = threadIdx.x, lane = tid & 63;
    __shared__ unsigned ul[36];
    __shared__ unsigned h[8192];
    __shared__ unsigned wbase;
    for (int i = tid; i < 8192; i += 256) h[i] = 0;
    if (tid < 32) ul[tid] = ulist0[cg * 32 + tid];
    if (tid >= 32 && tid < 36) ul[tid] = 0xFFFFFFFFu;
    if (tid == 0) wbase = 0;
    __syncthreads();

    unsigned* seg = cbuf + ((size_t)(cg * NCHUNK + chunk)) * CHSZ;
    const float4* p = reinterpret_cast<const float4*>(
        conf + (size_t)cg * Nn + (size_t)chunk * CHSZ);
    for (int it = 0; it < CHSZ / 1024; it++) {
        float4 v = p[it * 256 + tid];
        unsigned bb[4] = { __float_as_uint(v.x), __float_as_uint(v.y),
                           __float_as_uint(v.z), __float_as_uint(v.w) };
#pragma unroll
        for (int j = 0; j < 4; j++) {
            unsigned bits = bb[j];
            unsigned key  = bits >> 20;
            unsigned pos  = lb32(ul, key);
            bool m = (pos < 32u) && (ul[pos] == key);
            if (m) atomicAdd(&h[(pos << 8) + ((bits >> 12) & 255u)], 1u);
            unsigned long long mask = __ballot(m);
            unsigned tot = (unsigned)__popcll(mask);
            if (tot) {
                unsigned bs = 0;
                if (lane == 0) bs = atomicAdd(&wbase, tot);
                bs = __shfl(bs, 0);
                if (m) {
                    unsigned before = (unsigned)__popcll(mask & ((1ull << lane) - 1ull));
                    seg[bs + before] = (pos << 20) | (bits & 0xFFFFFu);
                }
            }
        }
    }
    __syncthreads();
    for (int i = tid; i < 8192; i += 256) {
        unsigned v = h[i];
        if (v) atomicAdd(&qhistA[(size_t)cg * 8192 + i], v);
    }
    unsigned cnt = wbase;
    unsigned padded = (cnt + 1023u) & ~1023u;
    for (unsigned i = cnt + tid; i < padded; i += 256) seg[i] = 0xFFFFFFFFu;
    if (tid == 0) counts[cg * NCHUNK + chunk] = padded;
}

// ---------------------------------------------------------------------------
// Refine L1 on compacted data. Element key = (p0<<8)|bits[19:12]; ulist1 is
// in the same compact coordinates (emitted by k_scanq). Hist bits[11:4].
// ---------------------------------------------------------------------------
__global__ __launch_bounds__(256) void k_refine1(
    const unsigned* __restrict__ cbuf, const unsigned* __restrict__ counts,
    const unsigned* __restrict__ ulist1, unsigned* __restrict__ qhistB)
{
    int cg = blockIdx.x >> 5, chunk = blockIdx.x & 31;
    int tid = threadIdx.x;
    __shared__ unsigned ul[36];
    __shared__ unsigned h[8192];
    for (int i = tid; i < 8192; i += 256) h[i] = 0;
    if (tid < 32) ul[tid] = ulist1[cg * 32 + tid];
    if (tid >= 32 && tid < 36) ul[tid] = 0xFFFFFFFFu;
    __syncthreads();

    const uint4* seg = reinterpret_cast<const uint4*>(
        cbuf + (size_t)(cg * NCHUNK + chunk) * CHSZ);
    unsigned cntP = counts[cg * NCHUNK + chunk];
    for (unsigned it = 0; it < cntP / 1024; it++) {
        uint4 w = seg[it * 256 + tid];
        unsigned ww[4] = { w.x, w.y, w.z, w.w };
#pragma unroll
        for (int j = 0; j < 4; j++) {
            unsigned v = ww[j];
            unsigned key = ((v >> 20) << 8) | ((v >> 12) & 255u);
            unsigned pos = lb32(ul, key);
            if (pos < 32u && ul[pos] == key)
                atomicAdd(&h[(pos << 8) + ((v >> 4) & 255u)], 1u);
        }
    }
    __syncthreads();
    for (int i = tid; i < 8192; i += 256) {
        unsigned v = h[i];
        if (v) atomicAdd(&qhistB[(size_t)cg * 8192 + i], v);
    }
}

// ---------------------------------------------------------------------------
// Refine L2 (final 4 bits) on compacted data. Two searches: ulist1 -> pos1,
// key2=(pos1<<8)|bits[11:4] in ulist2 -> pos2. Hist bits[3:0].
// ---------------------------------------------------------------------------
__global__ __launch_bounds__(256) void k_refine2(
    const unsigned* __restrict__ cbuf, const unsigned* __restrict__ counts,
    const unsigned* __restrict__ ulist1, const unsigned* __restrict__ ulist2,
    unsigned* __restrict__ qhistC)
{
    int cg = blockIdx.x >> 5, chunk = blockIdx.x & 31;
    int tid = threadIdx.x;
    __shared__ unsigned ul1[36], ul2[36];
    __shared__ unsigned h[512];
    for (int i = tid; i < 512; i += 256) h[i] = 0;
    if (tid < 32) { ul1[tid] = ulist1[cg * 32 + tid]; ul2[tid] = ulist2[cg * 32 + tid]; }
    if (tid >= 32 && tid < 36) { ul1[tid] = 0xFFFFFFFFu; ul2[tid] = 0xFFFFFFFFu; }
    __syncthreads();

    const uint4* seg = reinterpret_cast<const uint4*>(
        cbuf + (size_t)(cg * NCHUNK + chunk) * CHSZ);
    unsigned cntP = counts[cg * NCHUNK + chunk];
    for (unsigned it = 0; it < cntP / 1024; it++) {
        uint4 w = seg[it * 256 + tid];
        unsigned ww[4] = { w.x, w.y, w.z, w.w };
#pragma unroll
        for (int j = 0; j < 4; j++) {
            unsigned v = ww[j];
            unsigned key1 = ((v >> 20) << 8) | ((v >> 12) & 255u);
            unsigned pos1 = lb32(ul1, key1);
            if (pos1 < 32u && ul1[pos1] == key1) {
                unsigned key2 = (pos1 << 8) | ((v >> 4) & 255u);
                unsigned pos2 = lb32(ul2, key2);
                if (pos2 < 32u && ul2[pos2] == key2)
                    atomicAdd(&h[(pos2 << 4) + (v & 15u)], 1u);
            }
        }
    }
    __syncthreads();
    for (int i = tid; i < 512; i += 256) {
        unsigned v = h[i];
        if (v) atomicAdd(&qhistC[(size_t)cg * 512 + i], v);
    }
}

// ---------------------------------------------------------------------------
// Scan per-query histograms. EMIT=1: pick sym, extend qprefix by 8 bits, emit
// next ulist in compact coords (oldslot<<8|sym). EMIT=0: final 4-bit level ->
// reconstruct values -> edges.
// ---------------------------------------------------------------------------
template <int BINS, int EMIT>
__global__ void k_scanq(const unsigned* __restrict__ qhist,
                        unsigned* __restrict__ qprefix, unsigned* __restrict__ qresid,
                        unsigned* __restrict__ uslot, unsigned* __restrict__ ulist_next,
                        float* __restrict__ edges, int c0)
{
    int t = threadIdx.x, cg = t >> 5, q = t & 31;
    bool active = (q < NQ);
    unsigned npc = 0xFFFFFFFFu;
    if (active) {
        unsigned slot = uslot[t];
        unsigned r = qresid[t];
        const unsigned* hb = qhist + (size_t)cg * 32 * BINS + slot * BINS;
        unsigned cum = 0, sym = BINS - 1, nr = r;
        int found = 0;
        for (int b2 = 0; b2 < BINS; b2++) {
            unsigned cb = hb[b2];
            if (!found && r < cum + cb) { sym = (unsigned)b2; nr = r - cum; found = 1; }
            cum += cb;
        }
        qresid[t] = nr;
        qprefix[t] = (qprefix[t] << (EMIT ? 8 : 4)) | sym;
        npc = (slot << 8) | sym;
    }
    if (EMIT) {
        __shared__ unsigned sp[19 * 32];
        sp[t] = npc;
        __syncthreads();
        if (active) {
            const unsigned* row = sp + cg * 32;
            int rfull = 0, less = 0;
            for (int j = 0; j < NQ; j++) {
                unsigned pj = row[j];
                less  += (pj < npc);
                rfull += (pj < npc) || (pj == npc && j < q);
            }
            uslot[t] = (unsigned)less;
            ulist_next[cg * 32 + rfull] = npc;
        } else {
            ulist_next[cg * 32 + q] = 0xFFFFFFFFu;
        }
    } else {
        __shared__ float sv[19 * 32];
        sv[t] = active ? __uint_as_float(qprefix[t]) : 0.f;
        __syncthreads();
        if (q < 16) {
            const float* vals = sv + cg * 32;
            float e;
            if (q == 0)       e = vals[0];
            else if (q == 15) e = vals[29];
            else {
                double pos = (double)q * (double)Nn / 15.0;
                double fr  = pos - floor(pos);
                float v0 = vals[2 * q - 1], v1 = vals[2 * q];
                e = v0 + (float)fr * (v1 - v0);
            }
            edges[(size_t)(c0 + cg) * 16 + q] = e;
        }
    }
}

// ---------------------------------------------------------------------------
// Binning + accumulation. Suffix-sum register accumulators (R5 design).
// ---------------------------------------------------------------------------
__global__ __launch_bounds__(256) void k_bin(
    const float* __restrict__ conf, const int* __restrict__ labels,
    const float* __restrict__ edges, float* __restrict__ accum, int c0)
{
    int cgi   = blockIdx.x >> 7;       // class within group (BCH=128)
    int chunk = blockIdx.x & (BCH - 1);
    int tid   = threadIdx.x;
    int c     = c0 + cgi;

    float e[16];
#pragma unroll
    for (int i = 0; i < 16; i++) e[i] = edges[(size_t)c * 16 + i];

    float C[16], S[16], R[16];
#pragma unroll
    for (int i = 0; i < 16; i++) { C[i] = 0.f; S[i] = 0.f; R[i] = 0.f; }

    const float4* p  = reinterpret_cast<const float4*>(
        conf + (size_t)cgi * Nn + (size_t)chunk * BCHSZ);
    const int4*   lp = reinterpret_cast<const int4*>(
        labels + (size_t)chunk * BCHSZ);

    for (int it = 0; it < BCHSZ / 1024; it++) {      // 16 iters
        float4 v  = p[it * 256 + tid];
        int4   lb = lp[it * 256 + tid];
        float vv[4] = { v.x, v.y, v.z, v.w };
        int   ll[4] = { lb.x, lb.y, lb.z, lb.w };
#pragma unroll
        for (int j = 0; j < 4; j++) {
            float x     = vv[j];
            float corrf = (ll[j] == c) ? 1.f : 0.f;
#pragma unroll
            for (int i = 0; i < 16; i++) {
                float gm = (e[i] < x) ? 1.f : 0.f;
                C[i] += gm;
                S[i] = fmaf(gm, x,     S[i]);
                R[i] = fmaf(gm, corrf, R[i]);
            }
        }
    }

    __shared__ float red[4][45];
    int lane = tid & 63, wv = tid >> 6;
#pragma unroll
    for (int b = 0; b < NB; b++) {
        float a0 = C[b] - C[b + 1];
        float a1 = S[b] - S[b + 1];
        float a2 = R[b] - R[b + 1];
        for (int off = 32; off; off >>= 1) {
            a0 += __shfl_down(a0, off);
            a1 += __shfl_down(a1, off);
            a2 += __shfl_down(a2, off);
        }
        if (lane == 0) {
            red[wv][b * 3]     = a0;
            red[wv][b * 3 + 1] = a1;
            red[wv][b * 3 + 2] = a2;
        }
    }
    __syncthreads();
    if (tid < 45) {
        float s = red[0][tid] + red[1][tid] + red[2][tid] + red[3][tid];
        if (s != 0.f) atomicAdd(&accum[(size_t)c * 45 + tid], s);
    }
}

// ---------------------------------------------------------------------------
// Finalize: per-class aece + mean
// ---------------------------------------------------------------------------
__global__ void k_final(const float* __restrict__ accum, float* __restrict__ out)
{
    int c = threadIdx.x;
    __shared__ float pcs[Cn];
    if (c < Cn) {
        float pc = 0.f;
        for (int j = 0; j < NB; j++) {
            float cnt = accum[(c * NB + j) * 3];
            if (cnt > 0.f) {
                float sc  = accum[(c * NB + j) * 3 + 1];
                float scr = accum[(c * NB + j) * 3 + 2];
                float a   = scr / cnt;
                float avg = sc / cnt;
                float prop = cnt / (float)Nn;
                pc += fabsf(avg - a) * prop;
            }
        }
        pcs[c] = pc;
        out[1 + c] = pc;
    }
    __syncthreads();
    if (c == 0) {
        float s = 0.f;
        for (int j = 0; j < Cn; j++) s += pcs[j];
        out[0] = s / (float)Cn;
    }
}

// ---------------------------------------------------------------------------
extern "C" void kernel_launch(void* const* d_in, const int* in_sizes, int n_in,
                              void* d_out, int out_size, void* d_ws, size_t ws_size,
                              hipStream_t stream)
{
    const float* logits = (const float*)d_in[0];
    const int*   labels = (const int*)d_in[1];
    float* out = (float*)d_out;
    char*  ws  = (char*)d_ws;

    // Class-group sizing from available workspace
    size_t per_class = (size_t)Nn * 4                 // conf row
                     + (size_t)Nn * 4                 // compacted row
                     + (size_t)NCHUNK * 4096 * 4      // partial hists
                     + (2ull * 8192 + 512) * 4        // qhistA/B/C
                     + NCHUNK * 4;                    // counts
    size_t fixed = 65536;
    int gc = (ws_size > fixed) ? (int)((ws_size - fixed) / per_class) : 1;
    if (gc > Cn) gc = Cn;
    if (gc < 1)  gc = 1;
    int ng = (Cn + gc - 1) / gc;

    size_t off = 0;
    auto alloc = [&](size_t bytes) { size_t o = off; off += (bytes + 255) & ~(size_t)255; return o; };
    float*    conf    = (float*)(ws + alloc((size_t)gc * Nn * 4));
    unsigned* cbuf    = (unsigned*)(ws + alloc((size_t)gc * Nn * 4));
    unsigned* partial = (unsigned*)(ws + alloc((size_t)gc * NCHUNK * 4096 * 4));
    // qhistA/B/C contiguous (sizes are 256B multiples -> no pad between)
    unsigned* qhistA  = (unsigned*)(ws + alloc((size_t)gc * 8192 * 4));
    unsigned* qhistB  = (unsigned*)(ws + alloc((size_t)gc * 8192 * 4));
    unsigned* qhistC  = (unsigned*)(ws + alloc((size_t)gc * 512 * 4));
    unsigned* counts  = (unsigned*)(ws + alloc((size_t)gc * NCHUNK * 4));
    unsigned* qprefix = (unsigned*)(ws + alloc(19 * 32 * 4));
    unsigned* qresid  = (unsigned*)(ws + alloc(19 * 32 * 4));
    unsigned* uslot   = (unsigned*)(ws + alloc(19 * 32 * 4));
    unsigned* ulist0  = (unsigned*)(ws + alloc(19 * 32 * 4));
    unsigned* ulist1  = (unsigned*)(ws + alloc(19 * 32 * 4));
    unsigned* ulist2  = (unsigned*)(ws + alloc(19 * 32 * 4));
    float*    edges   = (float*)(ws + alloc(19 * 16 * 4));
    float*    accum   = (float*)(ws + alloc(19 * 45 * 4));

    hipMemsetAsync(accum, 0, 19 * 45 * 4, stream);
    for (int g = 0; g < ng; g++) {
        int c0 = g * gc;
        int gcc = (Cn - c0 < gc) ? (Cn - c0) : gc;
        // single memset covers qhistA+qhistB+qhistC (contiguous)
        hipMemsetAsync(qhistA, 0, (size_t)gc * (8192 + 8192) * 4 + (size_t)gcc * 512 * 4,
                       stream);

        k_softmax<<<N8 / 256, 256, 0, stream>>>(logits, conf, c0, gcc);
        k_hist12<<<gcc * NCHUNK, 256, 0, stream>>>(conf, partial);
        k_prep<<<gcc, 1024, 0, stream>>>(partial, qprefix, qresid, ulist0, uslot);
        k_refine0<<<gcc * NCHUNK, 256, 0, stream>>>(conf, ulist0, qhistA, cbuf, counts);
        k_scanq<256, 1><<<1, gcc * 32, 0, stream>>>(qhistA, qprefix, qresid, uslot,
                                                    ulist1, edges, c0);
        k_refine1<<<gcc * NCHUNK, 256, 0, stream>>>(cbuf, counts, ulist1, qhistB);
        k_scanq<256, 1><<<1, gcc * 32, 0, stream>>>(qhistB, qprefix, qresid, uslot,
                                                    ulist2, edges, c0);
        k_refine2<<<gcc * NCHUNK, 256, 0, stream>>>(cbuf, counts, ulist1, ulist2, qhistC);
        k_scanq<16, 0><<<1, gcc * 32, 0, stream>>>(qhistC, qprefix, qresid, uslot,
                                                   ulist0, edges, c0);
        k_bin<<<gcc * BCH, 256, 0, stream>>>(conf, labels, edges, accum, c0);
    }
    k_final<<<1, 64, 0, stream>>>(accum, out);
}

// Round 9
// 642.764 us; speedup vs baseline: 3.4072x; 1.1990x over previous
//
#include <hip/hip_runtime.h>
#include <cstdint>
#include <cmath>

// Problem constants (fixed by reference setup_inputs)
constexpr int Bn = 4, Cn = 19, Hn = 512, Wn = 1024;
constexpr int HW  = Hn * Wn;            // 524288 = 2^19
constexpr int Nn  = Bn * HW;            // 2097152 = 2^21
constexpr int N4  = Nn / 4;
constexpr int NB  = 15;                 // NBINS
constexpr int NQ  = 30;                 // rank queries per class
constexpr int NCHUNK = 32;              // chunks per class for hist/refine passes
constexpr int CHSZ = Nn / NCHUNK;       // 65536 elems per chunk
constexpr int BCH  = 128;               // k_bin chunks per class (occupancy)
constexpr int BCHSZ = Nn / BCH;         // 16384 elems per k_bin chunk

// ---------------------------------------------------------------------------
// Pass 1: softmax — pure streaming, NO atomics (R7-measured 92 us version).
// ---------------------------------------------------------------------------
__global__ __launch_bounds__(256) void k_softmax(
    const float* __restrict__ lg, float* __restrict__ conf, int c0, int gc)
{
    int t = blockIdx.x * 256 + threadIdx.x;
    if (t >= N4) return;
    int n  = t * 4;
    int b  = n >> 19;
    int hw = n & (HW - 1);
    const float* base = lg + ((size_t)(b * Cn) << 19) + hw;

    float4 x[Cn];
#pragma unroll
    for (int c = 0; c < Cn; c++)
        x[c] = *reinterpret_cast<const float4*>(base + ((size_t)c << 19));

    float4 m = x[0];
#pragma unroll
    for (int c = 1; c < Cn; c++) {
        m.x = fmaxf(m.x, x[c].x); m.y = fmaxf(m.y, x[c].y);
        m.z = fmaxf(m.z, x[c].z); m.w = fmaxf(m.w, x[c].w);
    }
    float4 s = make_float4(0.f, 0.f, 0.f, 0.f);
#pragma unroll
    for (int c = 0; c < Cn; c++) {
        x[c].x = __expf(x[c].x - m.x); s.x += x[c].x;
        x[c].y = __expf(x[c].y - m.y); s.y += x[c].y;
        x[c].z = __expf(x[c].z - m.z); s.z += x[c].z;
        x[c].w = __expf(x[c].w - m.w); s.w += x[c].w;
    }
    float4 inv = make_float4(1.f / s.x, 1.f / s.y, 1.f / s.z, 1.f / s.w);

#pragma unroll
    for (int c = 0; c < Cn; c++) {
        if (c < c0 || c >= c0 + gc) continue;   // uniform predicate, static idx
        float4 v;
        v.x = x[c].x * inv.x; v.y = x[c].y * inv.y;
        v.z = x[c].z * inv.z; v.w = x[c].w * inv.w;
        *reinterpret_cast<float4*>(conf + (size_t)(c - c0) * Nn + n) = v;
    }
}

// ---------------------------------------------------------------------------
// Pass 2: 12-bit (bits 31:20) LDS histogram, 4 replicas (one per wave),
// written as NON-atomic partial histograms per (class, chunk).
// ---------------------------------------------------------------------------
__global__ __launch_bounds__(256) void k_hist12(
    const float* __restrict__ conf, unsigned* __restrict__ partial)
{
    int cg = blockIdx.x >> 5, chunk = blockIdx.x & 31;
    int tid = threadIdx.x;
    __shared__ unsigned h[4 * 4096];
    for (int i = tid; i < 4 * 4096; i += 256) h[i] = 0;
    __syncthreads();
    unsigned* hr = h + ((tid >> 6) << 12);   // replica per wave

    const float4* p = reinterpret_cast<const float4*>(
        conf + (size_t)cg * Nn + (size_t)chunk * CHSZ);
    for (int it = 0; it < CHSZ / 1024; it++) {
        float4 v = p[it * 256 + tid];
        atomicAdd(&hr[__float_as_uint(v.x) >> 20], 1u);
        atomicAdd(&hr[__float_as_uint(v.y) >> 20], 1u);
        atomicAdd(&hr[__float_as_uint(v.z) >> 20], 1u);
        atomicAdd(&hr[__float_as_uint(v.w) >> 20], 1u);
    }
    __syncthreads();
    unsigned* out = partial + (((size_t)(cg * NCHUNK + chunk)) << 12);
    for (int i = tid; i < 4096; i += 256)
        out[i] = h[i] + h[4096 + i] + h[8192 + i] + h[12288 + i];
}

// rank of query slot s: 0 -> 0; 29 -> N-1; 2k-1 -> floor(k*N/15); 2k -> +1
__device__ __forceinline__ long long rank_of_slot(int s)
{
    if (s == 0)  return 0;
    if (s == 29) return (long long)Nn - 1;
    int k = (s & 1) ? ((s + 1) >> 1) : (s >> 1);
    double pos = (double)k * (double)Nn / 15.0;
    long long ik = (long long)floor(pos);
    return (s & 1) ? ik : ik + 1;
}

// ---------------------------------------------------------------------------
// Merged hred + scan + find: one block per class (1024 threads).
// ---------------------------------------------------------------------------
__global__ __launch_bounds__(1024) void k_prep(
    const unsigned* __restrict__ partial,
    unsigned* __restrict__ qprefix, unsigned* __restrict__ qresid,
    unsigned* __restrict__ ulist0, unsigned* __restrict__ uslot)
{
    int cg = blockIdx.x, t = threadIdx.x;
    __shared__ unsigned cum[4096];
    __shared__ unsigned ls[1024];
    __shared__ unsigned sp[32];

    int base = t * 4;
    unsigned b0 = 0, b1 = 0, b2 = 0, b3 = 0;
    for (int ch = 0; ch < NCHUNK; ch++) {
        const unsigned* pp = partial + (((size_t)(cg * NCHUNK + ch)) << 12) + base;
        b0 += pp[0]; b1 += pp[1]; b2 += pp[2]; b3 += pp[3];
    }
    unsigned s = b0 + b1 + b2 + b3;
    ls[t] = s; __syncthreads();
    for (int off = 1; off < 1024; off <<= 1) {
        unsigned v = (t >= off) ? ls[t - off] : 0u;
        __syncthreads();
        ls[t] += v;
        __syncthreads();
    }
    unsigned run = ls[t] - s;
    run += b0; cum[base]     = run;
    run += b1; cum[base + 1] = run;
    run += b2; cum[base + 2] = run;
    run += b3; cum[base + 3] = run;
    __syncthreads();

    unsigned p = 0xFFFFFFFFu, resid = 0;
    if (t < NQ) {
        long long r = rank_of_slot(t);
        unsigned pos = 0;
#pragma unroll
        for (int st = 2048; st >= 1; st >>= 1) {
            unsigned np = pos + st;
            if (cum[np - 1] <= (unsigned)r) pos = np;
        }
        unsigned prev = pos ? cum[pos - 1] : 0u;
        p = pos; resid = (unsigned)r - prev;
    }
    if (t < 32) sp[t] = p;
    __syncthreads();
    if (t < NQ) {
        int rfull = 0, less = 0;
        for (int j = 0; j < NQ; j++) {
            unsigned pj = sp[j];
            less  += (pj < p);
            rfull += (pj < p) || (pj == p && j < t);
        }
        qprefix[cg * 32 + t] = p;
        qresid[cg * 32 + t]  = resid;
        uslot[cg * 32 + t]   = (unsigned)less;
        ulist0[cg * 32 + rfull] = p;
    } else if (t < 32) {
        ulist0[cg * 32 + t] = 0xFFFFFFFFu;
    }
}

__device__ __forceinline__ unsigned lb32(const unsigned* ul, unsigned key)
{
    unsigned pos = (ul[15] < key) ? 16u : 0u;
    pos += (ul[pos + 7] < key) ? 8u : 0u;
    pos += (ul[pos + 3] < key) ? 4u : 0u;
    pos += (ul[pos + 1] < key) ? 2u : 0u;
    pos += (ul[pos]     < key) ? 1u : 0u;
    return pos;
}

// ---------------------------------------------------------------------------
// Refine L0 + compaction. NEW: one wave-append per 4-element group (4
// independent ballots + popc offsets + single wbase atomic) instead of 4
// serial ballot chains. Segment order is irrelevant downstream.
// ---------------------------------------------------------------------------
__global__ __launch_bounds__(256) void k_refine0(
    const float* __restrict__ conf, const unsigned* __restrict__ ulist0,
    unsigned* __restrict__ qhistA, unsigned* __restrict__ cbuf,
    unsigned* __restrict__ counts)
{
    int cg = blockIdx.x >> 5, chunk = blockIdx.x & 31;
    int tid = threadIdx.x, lane = tid & 63;
    __shared__ unsigned ul[36];
    __shared__ unsigned h[8192];
    __shared__ unsigned wbase;
    for (int i = tid; i < 8192; i += 256) h[i] = 0;
    if (tid < 32) ul[tid] = ulist0[cg * 32 + tid];
    if (tid >= 32 && tid < 36) ul[tid] = 0xFFFFFFFFu;
    if (tid == 0) wbase = 0;
    __syncthreads();

    unsigned* seg = cbuf + ((size_t)(cg * NCHUNK + chunk)) * CHSZ;
    const float4* p = reinterpret_cast<const float4*>(
        conf + (size_t)cg * Nn + (size_t)chunk * CHSZ);
    for (int it = 0; it < CHSZ / 1024; it++) {
        float4 v = p[it * 256 + tid];
        unsigned bb[4] = { __float_as_uint(v.x), __float_as_uint(v.y),
                           __float_as_uint(v.z), __float_as_uint(v.w) };
        unsigned wrd[4]; bool mm[4];
#pragma unroll
        for (int j = 0; j < 4; j++) {
            unsigned bits = bb[j];
            unsigned key  = bits >> 20;
            unsigned pos  = lb32(ul, key);
            bool m = (pos < 32u) && (ul[pos] == key);
            mm[j]  = m;
            wrd[j] = (pos << 20) | (bits & 0xFFFFFu);
            if (m) atomicAdd(&h[(pos << 8) + ((bits >> 12) & 255u)], 1u);
        }
        unsigned long long mk0 = __ballot(mm[0]);
        unsigned long long mk1 = __ballot(mm[1]);
        unsigned long long mk2 = __ballot(mm[2]);
        unsigned long long mk3 = __ballot(mm[3]);
        unsigned c0_ = (unsigned)__popcll(mk0), c1_ = (unsigned)__popcll(mk1);
        unsigned c2_ = (unsigned)__popcll(mk2), c3_ = (unsigned)__popcll(mk3);
        unsigned tot = c0_ + c1_ + c2_ + c3_;
        if (tot) {
            unsigned bs = 0;
            if (lane == 0) bs = atomicAdd(&wbase, tot);
            bs = __shfl(bs, 0);
            unsigned long long below = (lane == 63) ? 0x7FFFFFFFFFFFFFFFull
                                                    : ((1ull << lane) - 1ull);
            unsigned o = bs;
            if (mm[0]) seg[o + (unsigned)__popcll(mk0 & below)] = wrd[0];
            o += c0_;
            if (mm[1]) seg[o + (unsigned)__popcll(mk1 & below)] = wrd[1];
            o += c1_;
            if (mm[2]) seg[o + (unsigned)__popcll(mk2 & below)] = wrd[2];
            o += c2_;
            if (mm[3]) seg[o + (unsigned)__popcll(mk3 & below)] = wrd[3];
        }
    }
    __syncthreads();
    for (int i = tid; i < 8192; i += 256) {
        unsigned v = h[i];
        if (v) atomicAdd(&qhistA[(size_t)cg * 8192 + i], v);
    }
    unsigned cnt = wbase;
    unsigned padded = (cnt + 1023u) & ~1023u;
    for (unsigned i = cnt + tid; i < padded; i += 256) seg[i] = 0xFFFFFFFFu;
    if (tid == 0) counts[cg * NCHUNK + chunk] = padded;
}

// ---------------------------------------------------------------------------
// Refine L1 on compacted data.
// ---------------------------------------------------------------------------
__global__ __launch_bounds__(256) void k_refine1(
    const unsigned* __restrict__ cbuf, const unsigned* __restrict__ counts,
    const unsigned* __restrict__ ulist1, unsigned* __restrict__ qhistB)
{
    int cg = blockIdx.x >> 5, chunk = blockIdx.x & 31;
    int tid = threadIdx.x;
    __shared__ unsigned ul[36];
    __shared__ unsigned h[8192];
    for (int i = tid; i < 8192; i += 256) h[i] = 0;
    if (tid < 32) ul[tid] = ulist1[cg * 32 + tid];
    if (tid >= 32 && tid < 36) ul[tid] = 0xFFFFFFFFu;
    __syncthreads();

    const uint4* seg = reinterpret_cast<const uint4*>(
        cbuf + (size_t)(cg * NCHUNK + chunk) * CHSZ);
    unsigned cntP = counts[cg * NCHUNK + chunk];
    for (unsigned it = 0; it < cntP / 1024; it++) {
        uint4 w = seg[it * 256 + tid];
        unsigned ww[4] = { w.x, w.y, w.z, w.w };
#pragma unroll
        for (int j = 0; j < 4; j++) {
            unsigned v = ww[j];
            unsigned key = ((v >> 20) << 8) | ((v >> 12) & 255u);
            unsigned pos = lb32(ul, key);
            if (pos < 32u && ul[pos] == key)
                atomicAdd(&h[(pos << 8) + ((v >> 4) & 255u)], 1u);
        }
    }
    __syncthreads();
    for (int i = tid; i < 8192; i += 256) {
        unsigned v = h[i];
        if (v) atomicAdd(&qhistB[(size_t)cg * 8192 + i], v);
    }
}

// ---------------------------------------------------------------------------
// Refine L2 (final 4 bits) on compacted data.
// ---------------------------------------------------------------------------
__global__ __launch_bounds__(256) void k_refine2(
    const unsigned* __restrict__ cbuf, const unsigned* __restrict__ counts,
    const unsigned* __restrict__ ulist1, const unsigned* __restrict__ ulist2,
    unsigned* __restrict__ qhistC)
{
    int cg = blockIdx.x >> 5, chunk = blockIdx.x & 31;
    int tid = threadIdx.x;
    __shared__ unsigned ul1[36], ul2[36];
    __shared__ unsigned h[512];
    for (int i = tid; i < 512; i += 256) h[i] = 0;
    if (tid < 32) { ul1[tid] = ulist1[cg * 32 + tid]; ul2[tid] = ulist2[cg * 32 + tid]; }
    if (tid >= 32 && tid < 36) { ul1[tid] = 0xFFFFFFFFu; ul2[tid] = 0xFFFFFFFFu; }
    __syncthreads();

    const uint4* seg = reinterpret_cast<const uint4*>(
        cbuf + (size_t)(cg * NCHUNK + chunk) * CHSZ);
    unsigned cntP = counts[cg * NCHUNK + chunk];
    for (unsigned it = 0; it < cntP / 1024; it++) {
        uint4 w = seg[it * 256 + tid];
        unsigned ww[4] = { w.x, w.y, w.z, w.w };
#pragma unroll
        for (int j = 0; j < 4; j++) {
            unsigned v = ww[j];
            unsigned key1 = ((v >> 20) << 8) | ((v >> 12) & 255u);
            unsigned pos1 = lb32(ul1, key1);
            if (pos1 < 32u && ul1[pos1] == key1) {
                unsigned key2 = (pos1 << 8) | ((v >> 4) & 255u);
                unsigned pos2 = lb32(ul2, key2);
                if (pos2 < 32u && ul2[pos2] == key2)
                    atomicAdd(&h[(pos2 << 4) + (v & 15u)], 1u);
            }
        }
    }
    __syncthreads();
    for (int i = tid; i < 512; i += 256) {
        unsigned v = h[i];
        if (v) atomicAdd(&qhistC[(size_t)cg * 512 + i], v);
    }
}

// ---------------------------------------------------------------------------
// Scan per-query histograms; one block per class (32 threads).
// ---------------------------------------------------------------------------
template <int BINS, int EMIT>
__global__ void k_scanq(const unsigned* __restrict__ qhist,
                        unsigned* __restrict__ qprefix, unsigned* __restrict__ qresid,
                        unsigned* __restrict__ uslot, unsigned* __restrict__ ulist_next,
                        float* __restrict__ edges, int c0)
{
    int cg = blockIdx.x, q = threadIdx.x;
    int t = cg * 32 + q;
    bool active = (q < NQ);
    unsigned npc = 0xFFFFFFFFu;
    if (active) {
        unsigned slot = uslot[t];
        unsigned r = qresid[t];
        const unsigned* hb = qhist + (size_t)cg * 32 * BINS + slot * BINS;
        unsigned cum = 0, sym = BINS - 1, nr = r;
        int found = 0;
        for (int b2 = 0; b2 < BINS; b2++) {
            unsigned cb = hb[b2];
            if (!found && r < cum + cb) { sym = (unsigned)b2; nr = r - cum; found = 1; }
            cum += cb;
        }
        qresid[t] = nr;
        qprefix[t] = (qprefix[t] << (EMIT ? 8 : 4)) | sym;
        npc = (slot << 8) | sym;
    }
    if (EMIT) {
        __shared__ unsigned sp[32];
        sp[q] = npc;
        __syncthreads();
        if (active) {
            int rfull = 0, less = 0;
            for (int j = 0; j < NQ; j++) {
                unsigned pj = sp[j];
                less  += (pj < npc);
                rfull += (pj < npc) || (pj == npc && j < q);
            }
            uslot[t] = (unsigned)less;
            ulist_next[cg * 32 + rfull] = npc;
        } else {
            ulist_next[cg * 32 + q] = 0xFFFFFFFFu;
        }
    } else {
        __shared__ float sv[32];
        sv[q] = active ? __uint_as_float(qprefix[t]) : 0.f;
        __syncthreads();
        if (q < 16) {
            float e;
            if (q == 0)       e = sv[0];
            else if (q == 15) e = sv[29];
            else {
                double pos = (double)q * (double)Nn / 15.0;
                double fr  = pos - floor(pos);
                float v0 = sv[2 * q - 1], v1 = sv[2 * q];
                e = v0 + (float)fr * (v1 - v0);
            }
            edges[(size_t)(c0 + cg) * 16 + q] = e;
        }
    }
}

// ---------------------------------------------------------------------------
// Binning + accumulation. Suffix-sum register accumulators (R5 design).
// ---------------------------------------------------------------------------
__global__ __launch_bounds__(256) void k_bin(
    const float* __restrict__ conf, const int* __restrict__ labels,
    const float* __restrict__ edges, float* __restrict__ accum, int c0)
{
    int cgi   = blockIdx.x >> 7;       // class within group (BCH=128)
    int chunk = blockIdx.x & (BCH - 1);
    int tid   = threadIdx.x;
    int c     = c0 + cgi;

    float e[16];
#pragma unroll
    for (int i = 0; i < 16; i++) e[i] = edges[(size_t)c * 16 + i];

    float C[16], S[16], R[16];
#pragma unroll
    for (int i = 0; i < 16; i++) { C[i] = 0.f; S[i] = 0.f; R[i] = 0.f; }

    const float4* p  = reinterpret_cast<const float4*>(
        conf + (size_t)cgi * Nn + (size_t)chunk * BCHSZ);
    const int4*   lp = reinterpret_cast<const int4*>(
        labels + (size_t)chunk * BCHSZ);

    for (int it = 0; it < BCHSZ / 1024; it++) {      // 16 iters
        float4 v  = p[it * 256 + tid];
        int4   lb = lp[it * 256 + tid];
        float vv[4] = { v.x, v.y, v.z, v.w };
        int   ll[4] = { lb.x, lb.y, lb.z, lb.w };
#pragma unroll
        for (int j = 0; j < 4; j++) {
            float x     = vv[j];
            float corrf = (ll[j] == c) ? 1.f : 0.f;
#pragma unroll
            for (int i = 0; i < 16; i++) {
                float gm = (e[i] < x) ? 1.f : 0.f;
                C[i] += gm;
                S[i] = fmaf(gm, x,     S[i]);
                R[i] = fmaf(gm, corrf, R[i]);
            }
        }
    }

    __shared__ float red[4][45];
    int lane = tid & 63, wv = tid >> 6;
#pragma unroll
    for (int b = 0; b < NB; b++) {
        float a0 = C[b] - C[b + 1];
        float a1 = S[b] - S[b + 1];
        float a2 = R[b] - R[b + 1];
        for (int off = 32; off; off >>= 1) {
            a0 += __shfl_down(a0, off);
            a1 += __shfl_down(a1, off);
            a2 += __shfl_down(a2, off);
        }
        if (lane == 0) {
            red[wv][b * 3]     = a0;
            red[wv][b * 3 + 1] = a1;
            red[wv][b * 3 + 2] = a2;
        }
    }
    __syncthreads();
    if (tid < 45) {
        float s = red[0][tid] + red[1][tid] + red[2][tid] + red[3][tid];
        if (s != 0.f) atomicAdd(&accum[(size_t)c * 45 + tid], s);
    }
}

// ---------------------------------------------------------------------------
// Finalize: per-class aece + mean
// ---------------------------------------------------------------------------
__global__ void k_final(const float* __restrict__ accum, float* __restrict__ out)
{
    int c = threadIdx.x;
    __shared__ float pcs[Cn];
    if (c < Cn) {
        float pc = 0.f;
        for (int j = 0; j < NB; j++) {
            float cnt = accum[(c * NB + j) * 3];
            if (cnt > 0.f) {
                float sc  = accum[(c * NB + j) * 3 + 1];
                float scr = accum[(c * NB + j) * 3 + 2];
                float a   = scr / cnt;
                float avg = sc / cnt;
                float prop = cnt / (float)Nn;
                pc += fabsf(avg - a) * prop;
            }
        }
        pcs[c] = pc;
        out[1 + c] = pc;
    }
    __syncthreads();
    if (c == 0) {
        float s = 0.f;
        for (int j = 0; j < Cn; j++) s += pcs[j];
        out[0] = s / (float)Cn;
    }
}

// ---------------------------------------------------------------------------
extern "C" void kernel_launch(void* const* d_in, const int* in_sizes, int n_in,
                              void* d_out, int out_size, void* d_ws, size_t ws_size,
                              hipStream_t stream)
{
    const float* logits = (const float*)d_in[0];
    const int*   labels = (const int*)d_in[1];
    float* out = (float*)d_out;
    char*  ws  = (char*)d_ws;

    // Class-group sizing from available workspace
    size_t per_class = (size_t)Nn * 4                 // conf row
                     + (size_t)Nn * 4                 // compacted row
                     + (size_t)NCHUNK * 4096 * 4      // partial hists
                     + (2ull * 8192 + 512) * 4        // qhistA/B/C
                     + NCHUNK * 4;                    // counts
    size_t fixed = 65536;
    int gc = (ws_size > fixed) ? (int)((ws_size - fixed) / per_class) : 1;
    if (gc > Cn) gc = Cn;
    if (gc < 1)  gc = 1;
    int ng = (Cn + gc - 1) / gc;

    size_t off = 0;
    auto alloc = [&](size_t bytes) { size_t o = off; off += (bytes + 255) & ~(size_t)255; return o; };
    float*    conf    = (float*)(ws + alloc((size_t)gc * Nn * 4));
    unsigned* cbuf    = (unsigned*)(ws + alloc((size_t)gc * Nn * 4));
    unsigned* partial = (unsigned*)(ws + alloc((size_t)gc * NCHUNK * 4096 * 4));
    // qhistA/B/C contiguous (sizes are 256B multiples -> no pad between)
    unsigned* qhistA  = (unsigned*)(ws + alloc((size_t)gc * 8192 * 4));
    unsigned* qhistB  = (unsigned*)(ws + alloc((size_t)gc * 8192 * 4));
    unsigned* qhistC  = (unsigned*)(ws + alloc((size_t)gc * 512 * 4));
    unsigned* counts  = (unsigned*)(ws + alloc((size_t)gc * NCHUNK * 4));
    unsigned* qprefix = (unsigned*)(ws + alloc(19 * 32 * 4));
    unsigned* qresid  = (unsigned*)(ws + alloc(19 * 32 * 4));
    unsigned* uslot   = (unsigned*)(ws + alloc(19 * 32 * 4));
    unsigned* ulist0  = (unsigned*)(ws + alloc(19 * 32 * 4));
    unsigned* ulist1  = (unsigned*)(ws + alloc(19 * 32 * 4));
    unsigned* ulist2  = (unsigned*)(ws + alloc(19 * 32 * 4));
    float*    edges   = (float*)(ws + alloc(19 * 16 * 4));
    float*    accum   = (float*)(ws + alloc(19 * 45 * 4));

    hipMemsetAsync(accum, 0, 19 * 45 * 4, stream);
    for (int g = 0; g < ng; g++) {
        int c0 = g * gc;
        int gcc = (Cn - c0 < gc) ? (Cn - c0) : gc;
        // single memset covers qhistA+qhistB+qhistC (contiguous)
        hipMemsetAsync(qhistA, 0, (size_t)gc * (8192 + 8192) * 4 + (size_t)gcc * 512 * 4,
                       stream);

        k_softmax<<<N4 / 256, 256, 0, stream>>>(logits, conf, c0, gcc);
        k_hist12<<<gcc * NCHUNK, 256, 0, stream>>>(conf, partial);
        k_prep<<<gcc, 1024, 0, stream>>>(partial, qprefix, qresid, ulist0, uslot);
        k_refine0<<<gcc * NCHUNK, 256, 0, stream>>>(conf, ulist0, qhistA, cbuf, counts);
        k_scanq<256, 1><<<gcc, 32, 0, stream>>>(qhistA, qprefix, qresid, uslot,
                                                ulist1, edges, c0);
        k_refine1<<<gcc * NCHUNK, 256, 0, stream>>>(cbuf, counts, ulist1, qhistB);
        k_scanq<256, 1><<<gcc, 32, 0, stream>>>(qhistB, qprefix, qresid, uslot,
                                                ulist2, edges, c0);
        k_refine2<<<gcc * NCHUNK, 256, 0, stream>>>(cbuf, counts, ulist1, ulist2, qhistC);
        k_scanq<16, 0><<<gcc, 32, 0, stream>>>(qhistC, qprefix, qresid, uslot,
                                               ulist0, edges, c0);
        k_bin<<<gcc * BCH, 256, 0, stream>>>(conf, labels, edges, accum, c0);
    }
    k_final<<<1, 64, 0, stream>>>(accum, out);
}

// Round 11
// 583.156 us; speedup vs baseline: 3.7554x; 1.1022x over previous
//
#include <hip/hip_runtime.h>
#include <cstdint>
#include <cmath>

// Problem constants (fixed by reference setup_inputs)
constexpr int Bn = 4, Cn = 19, Hn = 512, Wn = 1024;
constexpr int HW  = Hn * Wn;            // 524288 = 2^19
constexpr int Nn  = Bn * HW;            // 2097152 = 2^21
constexpr int N4  = Nn / 4;
constexpr int NB  = 15;                 // NBINS
constexpr int NQ  = 30;                 // rank queries per class
constexpr int NCHUNK = 32;              // chunks per class for hist/refine passes
constexpr int CHSZ = Nn / NCHUNK;       // 65536 elems per chunk
constexpr int BCH  = 128;               // k_bin chunks per class (occupancy)
constexpr int BCHSZ = Nn / BCH;         // 16384 elems per k_bin chunk

// ---------------------------------------------------------------------------
// Pass 1: softmax — pure streaming, NO atomics (R7-measured 92 us version).
// ---------------------------------------------------------------------------
__global__ __launch_bounds__(256) void k_softmax(
    const float* __restrict__ lg, float* __restrict__ conf, int c0, int gc)
{
    int t = blockIdx.x * 256 + threadIdx.x;
    if (t >= N4) return;
    int n  = t * 4;
    int b  = n >> 19;
    int hw = n & (HW - 1);
    const float* base = lg + ((size_t)(b * Cn) << 19) + hw;

    float4 x[Cn];
#pragma unroll
    for (int c = 0; c < Cn; c++)
        x[c] = *reinterpret_cast<const float4*>(base + ((size_t)c << 19));

    float4 m = x[0];
#pragma unroll
    for (int c = 1; c < Cn; c++) {
        m.x = fmaxf(m.x, x[c].x); m.y = fmaxf(m.y, x[c].y);
        m.z = fmaxf(m.z, x[c].z); m.w = fmaxf(m.w, x[c].w);
    }
    float4 s = make_float4(0.f, 0.f, 0.f, 0.f);
#pragma unroll
    for (int c = 0; c < Cn; c++) {
        x[c].x = __expf(x[c].x - m.x); s.x += x[c].x;
        x[c].y = __expf(x[c].y - m.y); s.y += x[c].y;
        x[c].z = __expf(x[c].z - m.z); s.z += x[c].z;
        x[c].w = __expf(x[c].w - m.w); s.w += x[c].w;
    }
    float4 inv = make_float4(1.f / s.x, 1.f / s.y, 1.f / s.z, 1.f / s.w);

#pragma unroll
    for (int c = 0; c < Cn; c++) {
        if (c < c0 || c >= c0 + gc) continue;   // uniform predicate, static idx
        float4 v;
        v.x = x[c].x * inv.x; v.y = x[c].y * inv.y;
        v.z = x[c].z * inv.z; v.w = x[c].w * inv.w;
        *reinterpret_cast<float4*>(conf + (size_t)(c - c0) * Nn + n) = v;
    }
}

// ---------------------------------------------------------------------------
// Pass 2: 12-bit (bits 31:20) LDS histogram, 4 replicas (one per wave),
// written as NON-atomic partial histograms per (class, chunk).
// ---------------------------------------------------------------------------
__global__ __launch_bounds__(256) void k_hist12(
    const float* __restrict__ conf, unsigned* __restrict__ partial)
{
    int cg = blockIdx.x >> 5, chunk = blockIdx.x & 31;
    int tid = threadIdx.x;
    __shared__ unsigned h[4 * 4096];
    for (int i = tid; i < 4 * 4096; i += 256) h[i] = 0;
    __syncthreads();
    unsigned* hr = h + ((tid >> 6) << 12);   // replica per wave

    const float4* p = reinterpret_cast<const float4*>(
        conf + (size_t)cg * Nn + (size_t)chunk * CHSZ);
    for (int it = 0; it < CHSZ / 1024; it++) {
        float4 v = p[it * 256 + tid];
        atomicAdd(&hr[__float_as_uint(v.x) >> 20], 1u);
        atomicAdd(&hr[__float_as_uint(v.y) >> 20], 1u);
        atomicAdd(&hr[__float_as_uint(v.z) >> 20], 1u);
        atomicAdd(&hr[__float_as_uint(v.w) >> 20], 1u);
    }
    __syncthreads();
    unsigned* out = partial + (((size_t)(cg * NCHUNK + chunk)) << 12);
    for (int i = tid; i < 4096; i += 256)
        out[i] = h[i] + h[4096 + i] + h[8192 + i] + h[12288 + i];
}

// rank of query slot s: 0 -> 0; 29 -> N-1; 2k-1 -> floor(k*N/15); 2k -> +1
__device__ __forceinline__ long long rank_of_slot(int s)
{
    if (s == 0)  return 0;
    if (s == 29) return (long long)Nn - 1;
    int k = (s & 1) ? ((s + 1) >> 1) : (s >> 1);
    double pos = (double)k * (double)Nn / 15.0;
    long long ik = (long long)floor(pos);
    return (s & 1) ? ik : ik + 1;
}

// ---------------------------------------------------------------------------
// Merged hred + scan + find: one block per class (1024 threads).
// ---------------------------------------------------------------------------
__global__ __launch_bounds__(1024) void k_prep(
    const unsigned* __restrict__ partial,
    unsigned* __restrict__ qprefix, unsigned* __restrict__ qresid,
    unsigned* __restrict__ ulist0, unsigned* __restrict__ uslot)
{
    int cg = blockIdx.x, t = threadIdx.x;
    __shared__ unsigned cum[4096];
    __shared__ unsigned ls[1024];
    __shared__ unsigned sp[32];

    int base = t * 4;
    unsigned b0 = 0, b1 = 0, b2 = 0, b3 = 0;
    for (int ch = 0; ch < NCHUNK; ch++) {
        const unsigned* pp = partial + (((size_t)(cg * NCHUNK + ch)) << 12) + base;
        b0 += pp[0]; b1 += pp[1]; b2 += pp[2]; b3 += pp[3];
    }
    unsigned s = b0 + b1 + b2 + b3;
    ls[t] = s; __syncthreads();
    for (int off = 1; off < 1024; off <<= 1) {
        unsigned v = (t >= off) ? ls[t - off] : 0u;
        __syncthreads();
        ls[t] += v;
        __syncthreads();
    }
    unsigned run = ls[t] - s;
    run += b0; cum[base]     = run;
    run += b1; cum[base + 1] = run;
    run += b2; cum[base + 2] = run;
    run += b3; cum[base + 3] = run;
    __syncthreads();

    unsigned p = 0xFFFFFFFFu, resid = 0;
    if (t < NQ) {
        long long r = rank_of_slot(t);
        unsigned pos = 0;
#pragma unroll
        for (int st = 2048; st >= 1; st >>= 1) {
            unsigned np = pos + st;
            if (cum[np - 1] <= (unsigned)r) pos = np;
        }
        unsigned prev = pos ? cum[pos - 1] : 0u;
        p = pos; resid = (unsigned)r - prev;
    }
    if (t < 32) sp[t] = p;
    __syncthreads();
    if (t < NQ) {
        int rfull = 0, less = 0;
        for (int j = 0; j < NQ; j++) {
            unsigned pj = sp[j];
            less  += (pj < p);
            rfull += (pj < p) || (pj == p && j < t);
        }
        qprefix[cg * 32 + t] = p;
        qresid[cg * 32 + t]  = resid;
        uslot[cg * 32 + t]   = (unsigned)less;
        ulist0[cg * 32 + rfull] = p;
    } else if (t < 32) {
        ulist0[cg * 32 + t] = 0xFFFFFFFFu;
    }
}

// ---------------------------------------------------------------------------
// Refine L0 + compaction. Direct-mapped LDS table (4096 uchar: 12-bit prefix
// -> slot) replaces the 5-deep lb32 dependent-LDS chain. Table written from
// first occurrence of each value in the sorted ulist (== lower_bound pos).
// ---------------------------------------------------------------------------
__global__ __launch_bounds__(256) void k_refine0(
    const float* __restrict__ conf, const unsigned* __restrict__ ulist0,
    unsigned* __restrict__ qhistA, unsigned* __restrict__ cbuf,
    unsigned* __restrict__ counts)
{
    int cg = blockIdx.x >> 5, chunk = blockIdx.x & 31;
    int tid = threadIdx.x, lane = tid & 63;
    __shared__ unsigned char tbl[4096];
    __shared__ unsigned h[8192];
    __shared__ unsigned wbase;
    for (int i = tid; i < 8192; i += 256) h[i] = 0;
    for (int i = tid; i < 1024; i += 256)
        reinterpret_cast<unsigned*>(tbl)[i] = 0xFFFFFFFFu;
    if (tid == 0) wbase = 0;
    __syncthreads();
    if (tid < 32) {
        unsigned u  = ulist0[cg * 32 + tid];
        unsigned up = (tid == 0) ? 0xFFFFFFFFu : ulist0[cg * 32 + tid - 1];
        if (u < 4096u && u != up) tbl[u] = (unsigned char)tid;
    }
    __syncthreads();

    unsigned* seg = cbuf + ((size_t)(cg * NCHUNK + chunk)) * CHSZ;
    const float4* p = reinterpret_cast<const float4*>(
        conf + (size_t)cg * Nn + (size_t)chunk * CHSZ);
    for (int it = 0; it < CHSZ / 1024; it++) {
        float4 v = p[it * 256 + tid];
        unsigned bb[4] = { __float_as_uint(v.x), __float_as_uint(v.y),
                           __float_as_uint(v.z), __float_as_uint(v.w) };
        unsigned wrd[4]; bool mm[4];
#pragma unroll
        for (int j = 0; j < 4; j++) {
            unsigned bits = bb[j];
            unsigned slot = tbl[bits >> 20];      // conf in (0,1] -> key <= 1016
            bool m = (slot != 0xFFu);
            mm[j]  = m;
            wrd[j] = (slot << 20) | (bits & 0xFFFFFu);
            if (m) atomicAdd(&h[(slot << 8) + ((bits >> 12) & 255u)], 1u);
        }
        unsigned long long mk0 = __ballot(mm[0]);
        unsigned long long mk1 = __ballot(mm[1]);
        unsigned long long mk2 = __ballot(mm[2]);
        unsigned long long mk3 = __ballot(mm[3]);
        unsigned c0_ = (unsigned)__popcll(mk0), c1_ = (unsigned)__popcll(mk1);
        unsigned c2_ = (unsigned)__popcll(mk2), c3_ = (unsigned)__popcll(mk3);
        unsigned tot = c0_ + c1_ + c2_ + c3_;
        if (tot) {
            unsigned bs = 0;
            if (lane == 0) bs = atomicAdd(&wbase, tot);
            bs = __shfl(bs, 0);
            unsigned long long below = (lane == 63) ? 0x7FFFFFFFFFFFFFFFull
                                                    : ((1ull << lane) - 1ull);
            unsigned o = bs;
            if (mm[0]) seg[o + (unsigned)__popcll(mk0 & below)] = wrd[0];
            o += c0_;
            if (mm[1]) seg[o + (unsigned)__popcll(mk1 & below)] = wrd[1];
            o += c1_;
            if (mm[2]) seg[o + (unsigned)__popcll(mk2 & below)] = wrd[2];
            o += c2_;
            if (mm[3]) seg[o + (unsigned)__popcll(mk3 & below)] = wrd[3];
        }
    }
    __syncthreads();
    for (int i = tid; i < 8192; i += 256) {
        unsigned v = h[i];
        if (v) atomicAdd(&qhistA[(size_t)cg * 8192 + i], v);
    }
    unsigned cnt = wbase;
    unsigned padded = (cnt + 1023u) & ~1023u;
    for (unsigned i = cnt + tid; i < padded; i += 256) seg[i] = 0xFFFFFFFFu;
    if (tid == 0) counts[cg * NCHUNK + chunk] = padded;
}

// ---------------------------------------------------------------------------
// Refine L1 on compacted data. Table: 8192 uchar, key=(slot0<<8)|bits[19:12].
// Padding words give key >= 8192 -> guarded out.
// ---------------------------------------------------------------------------
__global__ __launch_bounds__(256) void k_refine1(
    const unsigned* __restrict__ cbuf, const unsigned* __restrict__ counts,
    const unsigned* __restrict__ ulist1, unsigned* __restrict__ qhistB)
{
    int cg = blockIdx.x >> 5, chunk = blockIdx.x & 31;
    int tid = threadIdx.x;
    __shared__ unsigned char tbl[8192];
    __shared__ unsigned h[8192];
    for (int i = tid; i < 8192; i += 256) h[i] = 0;
    for (int i = tid; i < 2048; i += 256)
        reinterpret_cast<unsigned*>(tbl)[i] = 0xFFFFFFFFu;
    __syncthreads();
    if (tid < 32) {
        unsigned u  = ulist1[cg * 32 + tid];
        unsigned up = (tid == 0) ? 0xFFFFFFFFu : ulist1[cg * 32 + tid - 1];
        if (u < 8192u && u != up) tbl[u] = (unsigned char)tid;
    }
    __syncthreads();

    const uint4* seg = reinterpret_cast<const uint4*>(
        cbuf + (size_t)(cg * NCHUNK + chunk) * CHSZ);
    unsigned cntP = counts[cg * NCHUNK + chunk];
    for (unsigned it = 0; it < cntP / 1024; it++) {
        uint4 w = seg[it * 256 + tid];
        unsigned ww[4] = { w.x, w.y, w.z, w.w };
#pragma unroll
        for (int j = 0; j < 4; j++) {
            unsigned v = ww[j];
            unsigned key = ((v >> 20) << 8) | ((v >> 12) & 255u);
            if (key < 8192u) {
                unsigned pos = tbl[key];
                if (pos != 0xFFu)
                    atomicAdd(&h[(pos << 8) + ((v >> 4) & 255u)], 1u);
            }
        }
    }
    __syncthreads();
    for (int i = tid; i < 8192; i += 256) {
        unsigned v = h[i];
        if (v) atomicAdd(&qhistB[(size_t)cg * 8192 + i], v);
    }
}

// ---------------------------------------------------------------------------
// Refine L2 (final 4 bits) on compacted data. Two table lookups.
// ---------------------------------------------------------------------------
__global__ __launch_bounds__(256) void k_refine2(
    const unsigned* __restrict__ cbuf, const unsigned* __restrict__ counts,
    const unsigned* __restrict__ ulist1, const unsigned* __restrict__ ulist2,
    unsigned* __restrict__ qhistC)
{
    int cg = blockIdx.x >> 5, chunk = blockIdx.x & 31;
    int tid = threadIdx.x;
    __shared__ unsigned char tbl1[8192], tbl2[8192];
    __shared__ unsigned h[512];
    for (int i = tid; i < 512; i += 256) h[i] = 0;
    for (int i = tid; i < 2048; i += 256) {
        reinterpret_cast<unsigned*>(tbl1)[i] = 0xFFFFFFFFu;
        reinterpret_cast<unsigned*>(tbl2)[i] = 0xFFFFFFFFu;
    }
    __syncthreads();
    if (tid < 32) {
        unsigned u  = ulist1[cg * 32 + tid];
        unsigned up = (tid == 0) ? 0xFFFFFFFFu : ulist1[cg * 32 + tid - 1];
        if (u < 8192u && u != up) tbl1[u] = (unsigned char)tid;
        unsigned u2  = ulist2[cg * 32 + tid];
        unsigned up2 = (tid == 0) ? 0xFFFFFFFFu : ulist2[cg * 32 + tid - 1];
        if (u2 < 8192u && u2 != up2) tbl2[u2] = (unsigned char)tid;
    }
    __syncthreads();

    const uint4* seg = reinterpret_cast<const uint4*>(
        cbuf + (size_t)(cg * NCHUNK + chunk) * CHSZ);
    unsigned cntP = counts[cg * NCHUNK + chunk];
    for (unsigned it = 0; it < cntP / 1024; it++) {
        uint4 w = seg[it * 256 + tid];
        unsigned ww[4] = { w.x, w.y, w.z, w.w };
#pragma unroll
        for (int j = 0; j < 4; j++) {
            unsigned v = ww[j];
            unsigned key1 = ((v >> 20) << 8) | ((v >> 12) & 255u);
            if (key1 < 8192u) {
                unsigned pos1 = tbl1[key1];
                if (pos1 != 0xFFu) {
                    unsigned key2 = (pos1 << 8) | ((v >> 4) & 255u);
                    unsigned pos2 = tbl2[key2];
                    if (pos2 != 0xFFu)
                        atomicAdd(&h[(pos2 << 4) + (v & 15u)], 1u);
                }
            }
        }
    }
    __syncthreads();
    for (int i = tid; i < 512; i += 256) {
        unsigned v = h[i];
        if (v) atomicAdd(&qhistC[(size_t)cg * 512 + i], v);
    }
}

// ---------------------------------------------------------------------------
// Scan per-query histograms; one block per class (32 threads).
// ---------------------------------------------------------------------------
template <int BINS, int EMIT>
__global__ void k_scanq(const unsigned* __restrict__ qhist,
                        unsigned* __restrict__ qprefix, unsigned* __restrict__ qresid,
                        unsigned* __restrict__ uslot, unsigned* __restrict__ ulist_next,
                        float* __restrict__ edges, int c0)
{
    int cg = blockIdx.x, q = threadIdx.x;
    int t = cg * 32 + q;
    bool active = (q < NQ);
    unsigned npc = 0xFFFFFFFFu;
    if (active) {
        unsigned slot = uslot[t];
        unsigned r = qresid[t];
        const unsigned* hb = qhist + (size_t)cg * 32 * BINS + slot * BINS;
        unsigned cum = 0, sym = BINS - 1, nr = r;
        int found = 0;
        for (int b2 = 0; b2 < BINS; b2++) {
            unsigned cb = hb[b2];
            if (!found && r < cum + cb) { sym = (unsigned)b2; nr = r - cum; found = 1; }
            cum += cb;
        }
        qresid[t] = nr;
        qprefix[t] = (qprefix[t] << (EMIT ? 8 : 4)) | sym;
        npc = (slot << 8) | sym;
    }
    if (EMIT) {
        __shared__ unsigned sp[32];
        sp[q] = npc;
        __syncthreads();
        if (active) {
            int rfull = 0, less = 0;
            for (int j = 0; j < NQ; j++) {
                unsigned pj = sp[j];
                less  += (pj < npc);
                rfull += (pj < npc) || (pj == npc && j < q);
            }
            uslot[t] = (unsigned)less;
            ulist_next[cg * 32 + rfull] = npc;
        } else {
            ulist_next[cg * 32 + q] = 0xFFFFFFFFu;
        }
    } else {
        __shared__ float sv[32];
        sv[q] = active ? __uint_as_float(qprefix[t]) : 0.f;
        __syncthreads();
        if (q < 16) {
            float e;
            if (q == 0)       e = sv[0];
            else if (q == 15) e = sv[29];
            else {
                double pos = (double)q * (double)Nn / 15.0;
                double fr  = pos - floor(pos);
                float v0 = sv[2 * q - 1], v1 = sv[2 * q];
                e = v0 + (float)fr * (v1 - v0);
            }
            edges[(size_t)(c0 + cg) * 16 + q] = e;
        }
    }
}

// ---------------------------------------------------------------------------
// Binning + accumulation. Suffix-sum register accumulators (R5 design).
// ---------------------------------------------------------------------------
__global__ __launch_bounds__(256) void k_bin(
    const float* __restrict__ conf, const int* __restrict__ labels,
    const float* __restrict__ edges, float* __restrict__ accum, int c0)
{
    int cgi   = blockIdx.x >> 7;       // class within group (BCH=128)
    int chunk = blockIdx.x & (BCH - 1);
    int tid   = threadIdx.x;
    int c     = c0 + cgi;

    float e[16];
#pragma unroll
    for (int i = 0; i < 16; i++) e[i] = edges[(size_t)c * 16 + i];

    float C[16], S[16], R[16];
#pragma unroll
    for (int i = 0; i < 16; i++) { C[i] = 0.f; S[i] = 0.f; R[i] = 0.f; }

    const float4* p  = reinterpret_cast<const float4*>(
        conf + (size_t)cgi * Nn + (size_t)chunk * BCHSZ);
    const int4*   lp = reinterpret_cast<const int4*>(
        labels + (size_t)chunk * BCHSZ);

    for (int it = 0; it < BCHSZ / 1024; it++) {      // 16 iters
        float4 v  = p[it * 256 + tid];
        int4   lb = lp[it * 256 + tid];
        float vv[4] = { v.x, v.y, v.z, v.w };
        int   ll[4] = { lb.x, lb.y, lb.z, lb.w };
#pragma unroll
        for (int j = 0; j < 4; j++) {
            float x     = vv[j];
            float corrf = (ll[j] == c) ? 1.f : 0.f;
#pragma unroll
            for (int i = 0; i < 16; i++) {
                float gm = (e[i] < x) ? 1.f : 0.f;
                C[i] += gm;
                S[i] = fmaf(gm, x,     S[i]);
                R[i] = fmaf(gm, corrf, R[i]);
            }
        }
    }

    __shared__ float red[4][45];
    int lane = tid & 63, wv = tid >> 6;
#pragma unroll
    for (int b = 0; b < NB; b++) {
        float a0 = C[b] - C[b + 1];
        float a1 = S[b] - S[b + 1];
        float a2 = R[b] - R[b + 1];
        for (int off = 32; off; off >>= 1) {
            a0 += __shfl_down(a0, off);
            a1 += __shfl_down(a1, off);
            a2 += __shfl_down(a2, off);
        }
        if (lane == 0) {
            red[wv][b * 3]     = a0;
            red[wv][b * 3 + 1] = a1;
            red[wv][b * 3 + 2] = a2;
        }
    }
    __syncthreads();
    if (tid < 45) {
        float s = red[0][tid] + red[1][tid] + red[2][tid] + red[3][tid];
        if (s != 0.f) atomicAdd(&accum[(size_t)c * 45 + tid], s);
    }
}

// ---------------------------------------------------------------------------
// Finalize: per-class aece + mean
// ---------------------------------------------------------------------------
__global__ void k_final(const float* __restrict__ accum, float* __restrict__ out)
{
    int c = threadIdx.x;
    __shared__ float pcs[Cn];
    if (c < Cn) {
        float pc = 0.f;
        for (int j = 0; j < NB; j++) {
            float cnt = accum[(c * NB + j) * 3];
            if (cnt > 0.f) {
                float sc  = accum[(c * NB + j) * 3 + 1];
                float scr = accum[(c * NB + j) * 3 + 2];
                float a   = scr / cnt;
                float avg = sc / cnt;
                float prop = cnt / (float)Nn;
                pc += fabsf(avg - a) * prop;
            }
        }
        pcs[c] = pc;
        out[1 + c] = pc;
    }
    __syncthreads();
    if (c == 0) {
        float s = 0.f;
        for (int j = 0; j < Cn; j++) s += pcs[j];
        out[0] = s / (float)Cn;
    }
}

// ---------------------------------------------------------------------------
extern "C" void kernel_launch(void* const* d_in, const int* in_sizes, int n_in,
                              void* d_out, int out_size, void* d_ws, size_t ws_size,
                              hipStream_t stream)
{
    const float* logits = (const float*)d_in[0];
    const int*   labels = (const int*)d_in[1];
    float* out = (float*)d_out;
    char*  ws  = (char*)d_ws;

    // Class-group sizing from available workspace
    size_t per_class = (size_t)Nn * 4                 // conf row
                     + (size_t)Nn * 4                 // compacted row
                     + (size_t)NCHUNK * 4096 * 4      // partial hists
                     + (2ull * 8192 + 512) * 4        // qhistA/B/C
                     + NCHUNK * 4;                    // counts
    size_t fixed = 65536;
    int gc = (ws_size > fixed) ? (int)((ws_size - fixed) / per_class) : 1;
    if (gc > Cn) gc = Cn;
    if (gc < 1)  gc = 1;
    int ng = (Cn + gc - 1) / gc;

    size_t off = 0;
    auto alloc = [&](size_t bytes) { size_t o = off; off += (bytes + 255) & ~(size_t)255; return o; };
    float*    conf    = (float*)(ws + alloc((size_t)gc * Nn * 4));
    unsigned* cbuf    = (unsigned*)(ws + alloc((size_t)gc * Nn * 4));
    unsigned* partial = (unsigned*)(ws + alloc((size_t)gc * NCHUNK * 4096 * 4));
    // qhistA/B/C contiguous (sizes are 256B multiples -> no pad between)
    unsigned* qhistA  = (unsigned*)(ws + alloc((size_t)gc * 8192 * 4));
    unsigned* qhistB  = (unsigned*)(ws + alloc((size_t)gc * 8192 * 4));
    unsigned* qhistC  = (unsigned*)(ws + alloc((size_t)gc * 512 * 4));
    unsigned* counts  = (unsigned*)(ws + alloc((size_t)gc * NCHUNK * 4));
    unsigned* qprefix = (unsigned*)(ws + alloc(19 * 32 * 4));
    unsigned* qresid  = (unsigned*)(ws + alloc(19 * 32 * 4));
    unsigned* uslot   = (unsigned*)(ws + alloc(19 * 32 * 4));
    unsigned* ulist0  = (unsigned*)(ws + alloc(19 * 32 * 4));
    unsigned* ulist1  = (unsigned*)(ws + alloc(19 * 32 * 4));
    unsigned* ulist2  = (unsigned*)(ws + alloc(19 * 32 * 4));
    float*    edges   = (float*)(ws + alloc(19 * 16 * 4));
    float*    accum   = (float*)(ws + alloc(19 * 45 * 4));

    hipMemsetAsync(accum, 0, 19 * 45 * 4, stream);
    for (int g = 0; g < ng; g++) {
        int c0 = g * gc;
        int gcc = (Cn - c0 < gc) ? (Cn - c0) : gc;
        // single memset covers qhistA+qhistB+qhistC (contiguous)
        hipMemsetAsync(qhistA, 0, (size_t)gc * (8192 + 8192) * 4 + (size_t)gcc * 512 * 4,
                       stream);

        k_softmax<<<N4 / 256, 256, 0, stream>>>(logits, conf, c0, gcc);
        k_hist12<<<gcc * NCHUNK, 256, 0, stream>>>(conf, partial);
        k_prep<<<gcc, 1024, 0, stream>>>(partial, qprefix, qresid, ulist0, uslot);
        k_refine0<<<gcc * NCHUNK, 256, 0, stream>>>(conf, ulist0, qhistA, cbuf, counts);
        k_scanq<256, 1><<<gcc, 32, 0, stream>>>(qhistA, qprefix, qresid, uslot,
                                                ulist1, edges, c0);
        k_refine1<<<gcc * NCHUNK, 256, 0, stream>>>(cbuf, counts, ulist1, qhistB);
        k_scanq<256, 1><<<gcc, 32, 0, stream>>>(qhistB, qprefix, qresid, uslot,
                                                ulist2, edges, c0);
        k_refine2<<<gcc * NCHUNK, 256, 0, stream>>>(cbuf, counts, ulist1, ulist2, qhistC);
        k_scanq<16, 0><<<gcc, 32, 0, stream>>>(qhistC, qprefix, qresid, uslot,
                                               ulist0, edges, c0);
        k_bin<<<gcc * BCH, 256, 0, stream>>>(conf, labels, edges, accum, c0);
    }
    k_final<<<1, 64, 0, stream>>>(accum, out);
}